// Round 14
// baseline (181.675 us; speedup 1.0000x reference)
//
#include <hip/hip_runtime.h>
#include <math.h>
#include <stdint.h>

// Sizes (fixed): B=2, S=L=1024, h=16, k=128, d_c=512, d_cq=1536, r=64, dim_q=2048

typedef __attribute__((ext_vector_type(8))) short short8;
typedef __attribute__((ext_vector_type(4))) float f32x4;

#define GLOAD16(gsrc, ldst)                                                            \
  __builtin_amdgcn_global_load_lds((const __attribute__((address_space(1))) void*)(gsrc), \
                                   (__attribute__((address_space(3))) void*)(ldst), 16, 0, 0)

__device__ inline uint16_t f2b(float x) {  // round-to-nearest-even f32 -> bf16
  uint32_t u = __builtin_bit_cast(uint32_t, x);
  u += 0x7fff + ((u >> 16) & 1);
  return (uint16_t)(u >> 16);
}
__device__ inline uint32_t cvtpk_bf16(float lo, float hi) {  // packs 2 f32 -> 2 bf16 (RNE)
  uint32_t d;
  asm("v_cvt_pk_bf16_f32 %0, %1, %2" : "=v"(d) : "v"(lo), "v"(hi));
  return d;
}

// ---------------- fused prep: 3x convert + rope tables + 3x transpose ----------------
// blocks: [0,512) kv | [512,1024) wkv | [1024,2560) wkcq | [2560,2816) tables |
// [2816,6912) Wq^T | [6912,8448) W_qr^T | [8448,8960) W_kr^T
__global__ __launch_bounds__(256) void prep_kernel(
    const float* __restrict__ s1, uint16_t* __restrict__ t1, const float* __restrict__ s2,
    uint16_t* __restrict__ t2, const float* __restrict__ s4, uint16_t* __restrict__ t4,
    float* __restrict__ cosK, float* __restrict__ sinK, float* __restrict__ cosQ,
    float* __restrict__ sinQ, const float* __restrict__ Wq, uint16_t* __restrict__ WqT,
    const float* __restrict__ W_qr, uint16_t* __restrict__ WqrT, const float* __restrict__ W_kr,
    uint16_t* __restrict__ WkrT) {
  __shared__ float t[32][33];
  int bid = blockIdx.x;
  if (bid >= 2816) {  // transpose segments
    int tb = bid - 2816;
    const float* src;
    uint16_t* dst;
    int R, C, r0, c0;
    if (tb < 4096) {
      src = Wq; dst = WqT; R = 2048; C = 2048;
      r0 = (tb & 63) * 32; c0 = (tb >> 6) * 32;
    } else if (tb < 5632) {
      int b = tb - 4096;
      int z = b / 96, rem = b % 96;
      src = W_qr + (size_t)z * 98304; dst = WqrT + (size_t)z * 98304;
      R = 1536; C = 64;
      r0 = (rem >> 1) * 32; c0 = (rem & 1) * 32;
    } else {
      int b = tb - 5632;
      int z = b / 32, rem = b % 32;
      src = W_kr + (size_t)z * 32768; dst = WkrT + (size_t)z * 32768;
      R = 512; C = 64;
      r0 = (rem >> 1) * 32; c0 = (rem & 1) * 32;
    }
    int tr = threadIdx.x >> 5, tc = threadIdx.x & 31;
#pragma unroll
    for (int i = 0; i < 4; ++i) t[tr + i * 8][tc] = src[(size_t)(r0 + tr + i * 8) * C + c0 + tc];
    __syncthreads();
#pragma unroll
    for (int i = 0; i < 4; ++i)
      dst[(size_t)(c0 + tr + i * 8) * R + r0 + tc] = f2b(t[tc][tr + i * 8]);
    return;
  }
  if (bid >= 2560) {  // rope tables
    const float LOG2E = 1.44269504088896341f;
    int idx = (bid - 2560) * 256 + threadIdx.x;
    int s = idx >> 6, j = idx & 63;
    int i = j & 31;
    float inv = powf(10000.0f, -(float)(2 * i) / 64.0f);
    float ang = (float)s * inv;
    float c = cosf(ang), sn = sinf(ang);
    cosK[idx] = c;
    sinK[idx] = sn;
    cosQ[idx] = c * LOG2E;
    sinQ[idx] = sn * LOG2E;
    return;
  }
  const float* s;
  uint16_t* tt;
  int off;
  if (bid < 512) { s = s1; tt = t1; off = bid; }
  else if (bid < 1024) { s = s2; tt = t2; off = bid - 512; }
  else { s = s4; tt = t4; off = bid - 1024; }
  int i = off * 256 + threadIdx.x;
  const float4* s4v = (const float4*)s;
  float4 a = s4v[i * 2], b = s4v[i * 2 + 1];
  uint4 v;
  v.x = cvtpk_bf16(a.x, a.y);
  v.y = cvtpk_bf16(a.z, a.w);
  v.z = cvtpk_bf16(b.x, b.y);
  v.w = cvtpk_bf16(b.z, b.w);
  ((uint4*)tt)[i] = v;
}

// ---------------- MFMA GEMM (generic bf16): C = A @ Bt^T, 64 x 128 tile, dbuf ----------------
// EPI 0: f32 row-major (z-linear via cZ). SPLITK>1: z = zh*SPLITK+zk, K-offset zk*K.
template <int BM, int EPI, int SPLITK = 1>
__global__ __launch_bounds__(256) void gemm_mfma_kernel(const uint16_t* __restrict__ A,
                                                        const uint16_t* __restrict__ Bt,
                                                        void* __restrict__ Cv, int K, int lda,
                                                        int ldb, int ldc, int aZ, int bZ,
                                                        int cZ) {
  constexpr int MT = BM / 32;
  __shared__ __align__(16) uint16_t As[2][BM * 64];
  __shared__ __align__(16) uint16_t Bs[2][128 * 64];
  int z = blockIdx.z;
  if (SPLITK > 1) {
    int zh = z / SPLITK, zk = z % SPLITK;
    A += (size_t)zh * aZ + (size_t)zk * K;
    Bt += (size_t)zh * bZ + (size_t)zk * K;
  } else {
    A += (size_t)z * aZ;
    Bt += (size_t)z * bZ;
  }
  int m0 = blockIdx.x * BM, n0 = blockIdx.y * 128;
  int tid = threadIdx.x;
  int wave = tid >> 6, lane = tid & 63;
  int wm = wave >> 1, wn = wave & 1;
  int rS = lane >> 3, sl = lane & 7;
  int lr = lane >> 4, lc = lane & 15;

  auto stage = [&](int k0, int buf) {
#pragma unroll
    for (int i = 0; i < MT; ++i) {
      int idx = wave * MT + i;
      int row = idx * 8 + rS;
      GLOAD16(A + (size_t)(m0 + row) * lda + k0 + ((sl ^ (row & 7)) << 3),
              (uint8_t*)As[buf] + idx * 1024);
    }
#pragma unroll
    for (int i = 0; i < 4; ++i) {
      int idx = wave * 4 + i;
      int row = idx * 8 + rS;
      GLOAD16(Bt + (size_t)(n0 + row) * ldb + k0 + ((sl ^ (row & 7)) << 3),
              (uint8_t*)Bs[buf] + idx * 1024);
    }
  };

  f32x4 acc[MT][4] = {};
  stage(0, 0);
  int cur = 0;
  for (int k0 = 0; k0 < K; k0 += 64) {
    __syncthreads();
    if (k0 + 64 < K) stage(k0 + 64, cur ^ 1);
    short8 af[MT][2], bf[4][2];
#pragma unroll
    for (int t = 0; t < MT; ++t)
#pragma unroll
      for (int ks = 0; ks < 2; ++ks) {
        int slot = ks * 4 + lr;
        int ra = wm * (BM / 2) + t * 16 + lc;
        af[t][ks] =
            *(const short8*)((const uint8_t*)As[cur] + ra * 128 + ((slot ^ (ra & 7)) << 4));
      }
#pragma unroll
    for (int t = 0; t < 4; ++t)
#pragma unroll
      for (int ks = 0; ks < 2; ++ks) {
        int slot = ks * 4 + lr;
        int rb = wn * 64 + t * 16 + lc;
        bf[t][ks] =
            *(const short8*)((const uint8_t*)Bs[cur] + rb * 128 + ((slot ^ (rb & 7)) << 4));
      }
    __builtin_amdgcn_s_setprio(1);
#pragma unroll
    for (int mt = 0; mt < MT; ++mt)
#pragma unroll
      for (int nt = 0; nt < 4; ++nt) {
        acc[mt][nt] =
            __builtin_amdgcn_mfma_f32_16x16x32_bf16(af[mt][0], bf[nt][0], acc[mt][nt], 0, 0, 0);
        acc[mt][nt] =
            __builtin_amdgcn_mfma_f32_16x16x32_bf16(af[mt][1], bf[nt][1], acc[mt][nt], 0, 0, 0);
      }
    __builtin_amdgcn_s_setprio(0);
    cur ^= 1;
  }
#pragma unroll
  for (int mt = 0; mt < MT; ++mt)
#pragma unroll
    for (int nt = 0; nt < 4; ++nt)
#pragma unroll
      for (int r = 0; r < 4; ++r) {
        int m = m0 + wm * (BM / 2) + mt * 16 + lr * 4 + r;
        int n = n0 + wn * 64 + nt * 16 + lc;
        float v = acc[mt][nt][r];
        if (EPI == 0)
          ((float*)Cv)[(size_t)z * cZ + (size_t)m * ldc + n] = v;
        else
          ((uint16_t*)Cv)[(size_t)z * cZ + (size_t)m * ldc + n] = f2b(v);
      }
}

// ---------------- fold2 fused: A = reduce8(tmp1[head]) in LDS; B = WqT staged ----------------
// grid (1, 16 ntiles, 16 heads), 256 thr. WfoldT[h*64+m][n] = sum_k A[m][k] * WqT[n][h*128+k]
__global__ __launch_bounds__(256) void fold2_kernel(const float* __restrict__ tmp1,
                                                    const uint16_t* __restrict__ WqT,
                                                    uint16_t* __restrict__ WfoldT) {
  __shared__ __align__(16) uint16_t As[2][64 * 64];
  __shared__ __align__(16) uint16_t Bs[2][128 * 64];
  int z = blockIdx.z;
  int n0 = blockIdx.y * 128;
  const uint16_t* Bt = WqT + z * 128;
  int tid = threadIdx.x;
  int wave = tid >> 6, lane = tid & 63;
  int wm = wave >> 1, wn = wave & 1;
  int rS = lane >> 3, sl = lane & 7;
  int lr = lane >> 4, lc = lane & 15;

  // A prefill: sum 8 f32 partials -> bf16, swizzled, into As[0] (k 0..63) and As[1] (k 64..127)
  {
    int row = tid >> 2;
    int kbase = (tid & 3) * 32;
    const float* tp = tmp1 + (size_t)z * 65536 + row * 128;
#pragma unroll
    for (int c = 0; c < 8; ++c) {
      int k4 = kbase + c * 4;
      float4 s = *(const float4*)(tp + k4);
#pragma unroll
      for (int p = 1; p < 8; ++p) {
        float4 sp = *(const float4*)(tp + p * 8192 + k4);
        s.x += sp.x;
        s.y += sp.y;
        s.z += sp.z;
        s.w += sp.w;
      }
      uint32_t lo = cvtpk_bf16(s.x, s.y);
      uint32_t hi = cvtpk_bf16(s.z, s.w);
      int buf = k4 >> 6, kl = k4 & 63;
      int slot = kl >> 3;
      uint32_t addr = row * 128 + ((slot ^ (row & 7)) << 4) + (kl & 7) * 2;
      *(uint32_t*)((uint8_t*)As[buf] + addr) = lo;
      *(uint32_t*)((uint8_t*)As[buf] + addr + 4) = hi;
    }
  }

  auto stageB = [&](int k0, int buf) {
#pragma unroll
    for (int i = 0; i < 4; ++i) {
      int idx = wave * 4 + i;
      int row = idx * 8 + rS;
      GLOAD16(Bt + (size_t)(n0 + row) * 2048 + k0 + ((sl ^ (row & 7)) << 3),
              (uint8_t*)Bs[buf] + idx * 1024);
    }
  };

  f32x4 acc[2][4] = {};
  stageB(0, 0);
  int cur = 0;
  for (int k0 = 0; k0 < 128; k0 += 64) {
    __syncthreads();  // drains gloads AND makes A-prefill ds_writes visible
    if (k0 + 64 < 128) stageB(64, 1);
    short8 af[2][2], bf[4][2];
#pragma unroll
    for (int t = 0; t < 2; ++t)
#pragma unroll
      for (int ks = 0; ks < 2; ++ks) {
        int slot = ks * 4 + lr;
        int ra = wm * 32 + t * 16 + lc;
        af[t][ks] =
            *(const short8*)((const uint8_t*)As[cur] + ra * 128 + ((slot ^ (ra & 7)) << 4));
      }
#pragma unroll
    for (int t = 0; t < 4; ++t)
#pragma unroll
      for (int ks = 0; ks < 2; ++ks) {
        int slot = ks * 4 + lr;
        int rb = wn * 64 + t * 16 + lc;
        bf[t][ks] =
            *(const short8*)((const uint8_t*)Bs[cur] + rb * 128 + ((slot ^ (rb & 7)) << 4));
      }
    __builtin_amdgcn_s_setprio(1);
#pragma unroll
    for (int mt = 0; mt < 2; ++mt)
#pragma unroll
      for (int nt = 0; nt < 4; ++nt) {
        acc[mt][nt] =
            __builtin_amdgcn_mfma_f32_16x16x32_bf16(af[mt][0], bf[nt][0], acc[mt][nt], 0, 0, 0);
        acc[mt][nt] =
            __builtin_amdgcn_mfma_f32_16x16x32_bf16(af[mt][1], bf[nt][1], acc[mt][nt], 0, 0, 0);
      }
    __builtin_amdgcn_s_setprio(0);
    cur ^= 1;
  }
#pragma unroll
  for (int mt = 0; mt < 2; ++mt)
#pragma unroll
    for (int nt = 0; nt < 4; ++nt)
#pragma unroll
      for (int r = 0; r < 4; ++r) {
        int m = wm * 32 + mt * 16 + lr * 4 + r;
        int n = n0 + wn * 64 + nt * 16 + lc;
        WfoldT[(size_t)z * 131072 + (size_t)m * 2048 + n] = f2b(acc[mt][nt][r]);
      }
}

// ---------------- triple GEMM: qr (y<8, f32 A) | kr (y<16) | VhT (y<32) ----------------
// grid (32, 32), 256 thr. qr: rope_q(hidden_q[f32] @ WfoldT^T); kr: rope_k(kvb @ WkrT^T);
// VhT: kvb @ wkvb^T in VhT layout. qr stages A from f32 with in-kernel convert.
__global__ __launch_bounds__(256) void gemm_triple_kernel(
    const float* __restrict__ hidden_q, const uint16_t* __restrict__ WfoldT,
    uint16_t* __restrict__ qrb, const uint16_t* __restrict__ kvb,
    const uint16_t* __restrict__ WkrT, uint16_t* __restrict__ krb,
    const uint16_t* __restrict__ wkvb, uint16_t* __restrict__ VhT,
    const float* __restrict__ cosQ, const float* __restrict__ sinQ,
    const float* __restrict__ cosK, const float* __restrict__ sinK) {
  __shared__ __align__(16) uint16_t As[2][64 * 64];
  __shared__ __align__(16) uint16_t Bs[2][128 * 64];
  int bx = blockIdx.x, byr = blockIdx.y;
  const uint16_t *Abf = nullptr, *Bt;
  uint16_t* Cv;
  const float *rc, *rs;
  int K, ldb, n0, mode;  // mode 0: rope bf16 out; 1: VhT layout
  bool aF32 = false;
  if (byr < 8) {
    aF32 = true; Bt = WfoldT; Cv = qrb; K = 2048; ldb = 2048;
    n0 = byr * 128; mode = 0; rc = cosQ; rs = sinQ;
  } else if (byr < 16) {
    Abf = kvb; Bt = WkrT; Cv = krb; K = 512; ldb = 512;
    n0 = (byr - 8) * 128; mode = 0; rc = cosK; rs = sinK;
  } else {
    Abf = kvb; Bt = wkvb; Cv = VhT; K = 512; ldb = 512;
    n0 = (byr - 16) * 128; mode = 1; rc = nullptr; rs = nullptr;
  }
  int m0 = bx * 64;
  int tid = threadIdx.x;
  int wave = tid >> 6, lane = tid & 63;
  int wm = wave >> 1, wn = wave & 1;
  int rS = lane >> 3, sl = lane & 7;
  int lr = lane >> 4, lc = lane & 15;

  auto stage = [&](int k0, int buf) {
    if (aF32) {
      // A from f32: 512 tasks (64 rows x 8 k-chunks), 2 per thread; cvt + swizzled ds_write_b128
#pragma unroll
      for (int i = 0; i < 2; ++i) {
        int task = tid * 2 + i;
        int row = task >> 3, c = task & 7;
        const float* src = hidden_q + (size_t)(m0 + row) * 2048 + k0 + c * 8;
        float4 a = *(const float4*)src;
        float4 b = *(const float4*)(src + 4);
        uint4 v;
        v.x = cvtpk_bf16(a.x, a.y);
        v.y = cvtpk_bf16(a.z, a.w);
        v.z = cvtpk_bf16(b.x, b.y);
        v.w = cvtpk_bf16(b.z, b.w);
        *(uint4*)((uint8_t*)As[buf] + row * 128 + ((c ^ (row & 7)) << 4)) = v;
      }
    } else {
#pragma unroll
      for (int i = 0; i < 2; ++i) {
        int idx = wave * 2 + i;
        int row = idx * 8 + rS;
        GLOAD16(Abf + (size_t)(m0 + row) * 512 + k0 + ((sl ^ (row & 7)) << 3),
                (uint8_t*)As[buf] + idx * 1024);
      }
    }
#pragma unroll
    for (int i = 0; i < 4; ++i) {
      int idx = wave * 4 + i;
      int row = idx * 8 + rS;
      GLOAD16(Bt + (size_t)(n0 + row) * ldb + k0 + ((sl ^ (row & 7)) << 3),
              (uint8_t*)Bs[buf] + idx * 1024);
    }
  };

  f32x4 acc[2][4] = {};
  stage(0, 0);
  int cur = 0;
  for (int k0 = 0; k0 < K; k0 += 64) {
    __syncthreads();
    if (k0 + 64 < K) stage(k0 + 64, cur ^ 1);
    short8 af[2][2], bf[4][2];
#pragma unroll
    for (int t = 0; t < 2; ++t)
#pragma unroll
      for (int ks = 0; ks < 2; ++ks) {
        int slot = ks * 4 + lr;
        int ra = wm * 32 + t * 16 + lc;
        af[t][ks] =
            *(const short8*)((const uint8_t*)As[cur] + ra * 128 + ((slot ^ (ra & 7)) << 4));
      }
#pragma unroll
    for (int t = 0; t < 4; ++t)
#pragma unroll
      for (int ks = 0; ks < 2; ++ks) {
        int slot = ks * 4 + lr;
        int rb = wn * 64 + t * 16 + lc;
        bf[t][ks] =
            *(const short8*)((const uint8_t*)Bs[cur] + rb * 128 + ((slot ^ (rb & 7)) << 4));
      }
    __builtin_amdgcn_s_setprio(1);
#pragma unroll
    for (int mt = 0; mt < 2; ++mt)
#pragma unroll
      for (int nt = 0; nt < 4; ++nt) {
        acc[mt][nt] =
            __builtin_amdgcn_mfma_f32_16x16x32_bf16(af[mt][0], bf[nt][0], acc[mt][nt], 0, 0, 0);
        acc[mt][nt] =
            __builtin_amdgcn_mfma_f32_16x16x32_bf16(af[mt][1], bf[nt][1], acc[mt][nt], 0, 0, 0);
      }
    __builtin_amdgcn_s_setprio(0);
    cur ^= 1;
  }
  if (mode == 0) {
#pragma unroll
    for (int mt = 0; mt < 2; ++mt)
#pragma unroll
      for (int nt = 0; nt < 4; ++nt)
#pragma unroll
        for (int r = 0; r < 4; ++r) {
          int m = m0 + wm * 32 + mt * 16 + lr * 4 + r;
          int n = n0 + wn * 64 + nt * 16 + lc;
          int pos = m & 1023, j = n & 63;
          float x = acc[mt][nt][r];
          float prt = acc[mt][nt ^ 2][r];
          float rot = (nt & 2) ? prt : -prt;
          float v = fmaf(x, rc[pos * 64 + j], rot * rs[pos * 64 + j]);
          Cv[(size_t)m * 1024 + n] = f2b(v);
        }
  } else {
#pragma unroll
    for (int mt = 0; mt < 2; ++mt)
#pragma unroll
      for (int nt = 0; nt < 4; ++nt)
#pragma unroll
        for (int r = 0; r < 4; ++r) {
          int m = m0 + wm * 32 + mt * 16 + lr * 4 + r;
          int n = n0 + wn * 64 + nt * 16 + lc;
          Cv[((size_t)((m >> 10) * 2048 + n)) * 1024 + (m & 1023)] = f2b(acc[mt][nt][r]);
        }
  }
}

// ---------------- out GEMM: out[f32] = ctxlatb @ Wo^T, B staged from f32, XCD-swizzled ----
// grid (32, 16), 256 thr, 64 x 128 tile, dbuf.
__global__ __launch_bounds__(256) void gemm_out_kernel(const uint16_t* __restrict__ A,
                                                       const float* __restrict__ Wo,
                                                       float* __restrict__ C) {
  __shared__ __align__(16) uint16_t As[2][64 * 64];
  __shared__ __align__(16) uint16_t Bs[2][128 * 64];
  // bijective XCD swizzle (512 blocks / 8 XCDs = 64-chunks): same-XCD blocks share B-panels
  int lin = blockIdx.x + 32 * blockIdx.y;
  int swz = (lin & 7) * 64 + (lin >> 3);
  int m0 = (swz & 31) * 64, n0 = (swz >> 5) * 128;
  int tid = threadIdx.x;
  int wave = tid >> 6, lane = tid & 63;
  int wm = wave >> 1, wn = wave & 1;
  int rS = lane >> 3, sl = lane & 7;
  int lr = lane >> 4, lc = lane & 15;

  auto stage = [&](int k0, int buf) {
#pragma unroll
    for (int i = 0; i < 2; ++i) {
      int idx = wave * 2 + i;
      int row = idx * 8 + rS;
      GLOAD16(A + (size_t)(m0 + row) * 2048 + k0 + ((sl ^ (row & 7)) << 3),
              (uint8_t*)As[buf] + idx * 1024);
    }
    // B from f32 Wo: 1024 tasks (128 rows x 8 chunks), 4 per thread
#pragma unroll
    for (int i = 0; i < 4; ++i) {
      int task = tid * 4 + i;
      int row = task >> 3, c = task & 7;
      const float* src = Wo + (size_t)(n0 + row) * 2048 + k0 + c * 8;
      float4 a = *(const float4*)src;
      float4 b = *(const float4*)(src + 4);
      uint4 v;
      v.x = cvtpk_bf16(a.x, a.y);
      v.y = cvtpk_bf16(a.z, a.w);
      v.z = cvtpk_bf16(b.x, b.y);
      v.w = cvtpk_bf16(b.z, b.w);
      *(uint4*)((uint8_t*)Bs[buf] + row * 128 + ((c ^ (row & 7)) << 4)) = v;
    }
  };

  f32x4 acc[2][4] = {};
  stage(0, 0);
  int cur = 0;
  for (int k0 = 0; k0 < 2048; k0 += 64) {
    __syncthreads();
    if (k0 + 64 < 2048) stage(k0 + 64, cur ^ 1);
    short8 af[2][2], bf[4][2];
#pragma unroll
    for (int t = 0; t < 2; ++t)
#pragma unroll
      for (int ks = 0; ks < 2; ++ks) {
        int slot = ks * 4 + lr;
        int ra = wm * 32 + t * 16 + lc;
        af[t][ks] =
            *(const short8*)((const uint8_t*)As[cur] + ra * 128 + ((slot ^ (ra & 7)) << 4));
      }
#pragma unroll
    for (int t = 0; t < 4; ++t)
#pragma unroll
      for (int ks = 0; ks < 2; ++ks) {
        int slot = ks * 4 + lr;
        int rb = wn * 64 + t * 16 + lc;
        bf[t][ks] =
            *(const short8*)((const uint8_t*)Bs[cur] + rb * 128 + ((slot ^ (rb & 7)) << 4));
      }
    __builtin_amdgcn_s_setprio(1);
#pragma unroll
    for (int mt = 0; mt < 2; ++mt)
#pragma unroll
      for (int nt = 0; nt < 4; ++nt) {
        acc[mt][nt] =
            __builtin_amdgcn_mfma_f32_16x16x32_bf16(af[mt][0], bf[nt][0], acc[mt][nt], 0, 0, 0);
        acc[mt][nt] =
            __builtin_amdgcn_mfma_f32_16x16x32_bf16(af[mt][1], bf[nt][1], acc[mt][nt], 0, 0, 0);
      }
    __builtin_amdgcn_s_setprio(0);
    cur ^= 1;
  }
#pragma unroll
  for (int mt = 0; mt < 2; ++mt)
#pragma unroll
    for (int nt = 0; nt < 4; ++nt)
#pragma unroll
      for (int r = 0; r < 4; ++r) {
        int m = m0 + wm * 32 + mt * 16 + lr * 4 + r;
        int n = n0 + wn * 64 + nt * 16 + lc;
        C[(size_t)m * 2048 + n] = acc[mt][nt][r];
      }
}

// ---------------- MFMA flash attention, swapped QK^T, Q-split 8 waves, FIXED-MAX softmax ----
// grid (bh=32, stile=8), 512 thr = 8 waves; wave owns q-rows s0 + wave*16 .. +15; all waves share
// one dbuf K/V tile (3 gloads/wave), ONE barrier/iter, prefetch-under-compute.
// Softmax uses FIXED max M=8 (exp2 domain; exact by shift-invariance — scores are O(1)).
// Out: ctxlatb bf16 [b*1024+s][2048]
__global__ __launch_bounds__(512, 2) void flash3_kernel(const uint16_t* __restrict__ qrb,
                                                        const uint16_t* __restrict__ krb,
                                                        const uint16_t* __restrict__ VhT,
                                                        uint16_t* __restrict__ ctxlatb) {
  // LDS: Ks[2][8192] @0 | Vs[2][16384] @16384 | Ps[8][2304] @49152  (total 67584 B)
  __shared__ __align__(16) uint8_t lds[67584];
  int bh = blockIdx.x;
  int b = bh >> 4, h = bh & 15;
  int s0 = blockIdx.y * 128;
  int tid = threadIdx.x, wave = tid >> 6, lane = tid & 63;
  int lr = lane >> 4, lc = lane & 15;
  int rS = lane >> 3, sl = lane & 7;

  uint8_t* Ps = lds + 49152 + wave * 2304;

  const uint16_t* qrow = qrb + (size_t)(b * 1024 + s0 + wave * 16 + lc) * 1024 + h * 64;
  short8 qa[2];
  qa[0] = *(const short8*)(qrow + lr * 8);
  qa[1] = *(const short8*)(qrow + 32 + lr * 8);

  float l_run = 0.f;
  f32x4 o[8] = {};

  uint8_t* psW = Ps + lc * 144 + lr * 8;
  const uint8_t* psR = Ps + lc * 144 + lr * 16;

  const uint16_t* krbase = krb + (size_t)(b * 1024) * 1024 + h * 64;
  const uint16_t* vtbase = VhT + (size_t)(b * 2048 + h * 128) * 1024;

  auto stageKV = [&](int l0, int buf) {
#pragma unroll
    for (int i = 0; i < 3; ++i) {
      int g = wave * 3 + i;
      if (g < 8) {
        int row = g * 8 + rS;
        GLOAD16(krbase + (size_t)(l0 + row) * 1024 + ((sl ^ (row & 7)) << 3),
                lds + buf * 8192 + g * 1024);
      } else {
        int v = g - 8;
        int row = v * 8 + rS;
        GLOAD16(vtbase + (size_t)row * 1024 + l0 + ((sl ^ (row & 7)) << 3),
                lds + 16384 + buf * 16384 + v * 1024);
      }
    }
  };

  stageKV(0, 0);
  int cur = 0;
  for (int t = 0; t < 16; ++t) {
    __syncthreads();
    if (t < 15) stageKV((t + 1) * 64, cur ^ 1);
    const uint8_t* Ks = lds + cur * 8192;
    const uint8_t* Vs = lds + 16384 + cur * 16384;

    f32x4 sc[4];
    __builtin_amdgcn_s_setprio(1);
#pragma unroll
    for (int nt = 0; nt < 4; ++nt) {
      int rowk = nt * 16 + lc;
      short8 kb0 = *(const short8*)(Ks + rowk * 128 + ((lr ^ (rowk & 7)) << 4));
      short8 kb1 = *(const short8*)(Ks + rowk * 128 + (((4 + lr) ^ (rowk & 7)) << 4));
      f32x4 z = {};
      z = __builtin_amdgcn_mfma_f32_16x16x32_bf16(kb0, qa[0], z, 0, 0, 0);
      sc[nt] = __builtin_amdgcn_mfma_f32_16x16x32_bf16(kb1, qa[1], z, 0, 0, 0);
    }
    __builtin_amdgcn_s_setprio(0);

    float ps = 0.f;
#pragma unroll
    for (int nt = 0; nt < 4; ++nt) {
#pragma unroll
      for (int rp = 0; rp < 2; ++rp) {
        float p0 = exp2f(sc[nt][rp * 2] - 8.0f);
        float p1 = exp2f(sc[nt][rp * 2 + 1] - 8.0f);
        ps += p0 + p1;
        *(uint32_t*)(psW + nt * 32 + rp * 4) = cvtpk_bf16(p0, p1);
      }
    }
    l_run += ps;

    short8 pa[2];
    pa[0] = *(const short8*)(psR);
    pa[1] = *(const short8*)(psR + 64);
    __builtin_amdgcn_s_setprio(1);
#pragma unroll
    for (int nt = 0; nt < 8; ++nt) {
      int rowv = nt * 16 + lc;
      short8 vb0 = *(const short8*)(Vs + rowv * 128 + ((lr ^ (rowv & 7)) << 4));
      short8 vb1 = *(const short8*)(Vs + rowv * 128 + (((4 + lr) ^ (rowv & 7)) << 4));
      o[nt] = __builtin_amdgcn_mfma_f32_16x16x32_bf16(pa[0], vb0, o[nt], 0, 0, 0);
      o[nt] = __builtin_amdgcn_mfma_f32_16x16x32_bf16(pa[1], vb1, o[nt], 0, 0, 0);
    }
    __builtin_amdgcn_s_setprio(0);
    cur ^= 1;
  }

  l_run += __shfl_xor(l_run, 16);
  l_run += __shfl_xor(l_run, 32);
  float li[4];
#pragma unroll
  for (int r = 0; r < 4; ++r) li[r] = 1.0f / __shfl(l_run, lr * 4 + r);
  uint16_t* orow = ctxlatb + (size_t)(b * 1024 + s0 + wave * 16) * 2048 + h * 128;
#pragma unroll
  for (int nt = 0; nt < 8; ++nt)
#pragma unroll
    for (int r = 0; r < 4; ++r)
      orow[(size_t)(lr * 4 + r) * 2048 + nt * 16 + lc] = f2b(o[nt][r] * li[r]);
}

extern "C" void kernel_launch(void* const* d_in, const int* in_sizes, int n_in,
                              void* d_out, int out_size, void* d_ws, size_t ws_size,
                              hipStream_t stream) {
  const float* hidden_q = (const float*)d_in[0];
  const float* kv_c = (const float*)d_in[1];
  const float* Wq = (const float*)d_in[2];
  const float* w_kc_q = (const float*)d_in[3];
  const float* W_qr = (const float*)d_in[4];
  const float* W_kr = (const float*)d_in[5];
  const float* w_kc_kv = (const float*)d_in[6];
  const float* Wo = (const float*)d_in[7];
  float* out = (float*)d_out;

  const size_t MB = 1024 * 1024;
  uint8_t* base = (uint8_t*)d_ws;
  uint16_t* qrb = (uint16_t*)(base + 0 * MB);       // 4 MiB [2048][1024] (q pre-scaled log2e)
  uint16_t* krb = (uint16_t*)(base + 4 * MB);       // 4 MiB [2048][1024]
  uint16_t* VhT = (uint16_t*)(base + 8 * MB);       // 8 MiB [b*2048+h*128+kk][1024]
  uint16_t* ctxlatb = (uint16_t*)(base + 16 * MB);  // 8 MiB [b*1024+s][2048]
  float* cosK = (float*)(base + 24 * MB);
  float* sinK = (float*)(base + 24 * MB + 262144);
  float* cosQ = (float*)(base + 24 * MB + 524288);
  float* sinQ = (float*)(base + 24 * MB + 786432);
  uint16_t* kvb = (uint16_t*)(base + 25 * MB);      // 2 MiB
  uint16_t* wkvb = (uint16_t*)(base + 27 * MB);     // 2 MiB
  uint16_t* WqT = (uint16_t*)(base + 29 * MB);      // 8 MiB
  uint16_t* WqrT = (uint16_t*)(base + 37 * MB);     // 3 MiB
  uint16_t* wkcqb = (uint16_t*)(base + 40 * MB);    // 6 MiB
  float* tmp1 = (float*)(base + 46 * MB);           // 4 MiB f32 fold1 partials [16][8][8192]
  uint16_t* WkrT = (uint16_t*)(base + 50 * MB);     // 1 MiB

  // fused prep: 3 converts + rope tables + 3 transposes (8960 blocks)
  prep_kernel<<<dim3(8960), dim3(256), 0, stream>>>(kv_c, kvb, w_kc_kv, wkvb, w_kc_q, wkcqb, cosK,
                                                    sinK, cosQ, sinQ, Wq, WqT, (const float*)W_qr,
                                                    WqrT, (const float*)W_kr, WkrT);
  // fold1 split-K x8: tmp1[h*8+zk] = partial sum over q in [zk*192,(zk+1)*192)
  gemm_mfma_kernel<64, 0, 8><<<dim3(1, 1, 128), dim3(256), 0, stream>>>(
      WqrT, wkcqb, tmp1, 192, 1536, 1536, 128, 98304, 196608, 8192);
  // fold2 (fused 8-partial reduce in A-prefill): WfoldT[h*64+r][d]
  uint16_t* WfoldT = wkcqb;  // overlays wkcqb (dead after fold1)
  fold2_kernel<<<dim3(1, 16, 16), dim3(256), 0, stream>>>(tmp1, WqT, WfoldT);
  // triple GEMM: qr (f32 A + rope_q) + kr (rope_k) + VhT in one launch
  gemm_triple_kernel<<<dim3(32, 32), dim3(256), 0, stream>>>(
      hidden_q, WfoldT, qrb, kvb, WkrT, krb, wkvb, VhT, cosQ, sinQ, cosK, sinK);
  // fused flash attention (Q-split 8 waves, shared dbuf staging, fixed-max softmax) -> ctxlatb
  flash3_kernel<<<dim3(32, 8), dim3(512), 0, stream>>>(qrb, krb, VhT, ctxlatb);
  // out = ctxlatb @ Wo^T (f32 B in-kernel convert, XCD-swizzled)
  gemm_out_kernel<<<dim3(32, 16), dim3(256), 0, stream>>>(ctxlatb, Wo, out);
}

// Round 15
// 133.546 us; speedup vs baseline: 1.3604x; 1.3604x over previous
//
#include <hip/hip_runtime.h>
#include <math.h>
#include <stdint.h>

// Sizes (fixed): B=2, S=L=1024, h=16, k=128, d_c=512, d_cq=1536, r=64, dim_q=2048

typedef __attribute__((ext_vector_type(8))) short short8;
typedef __attribute__((ext_vector_type(4))) float f32x4;

#define GLOAD16(gsrc, ldst)                                                            \
  __builtin_amdgcn_global_load_lds((const __attribute__((address_space(1))) void*)(gsrc), \
                                   (__attribute__((address_space(3))) void*)(ldst), 16, 0, 0)

__device__ inline uint16_t f2b(float x) {  // round-to-nearest-even f32 -> bf16
  uint32_t u = __builtin_bit_cast(uint32_t, x);
  u += 0x7fff + ((u >> 16) & 1);
  return (uint16_t)(u >> 16);
}
__device__ inline uint32_t cvtpk_bf16(float lo, float hi) {  // packs 2 f32 -> 2 bf16 (RNE)
  uint32_t d;
  asm("v_cvt_pk_bf16_f32 %0, %1, %2" : "=v"(d) : "v"(lo), "v"(hi));
  return d;
}

// ---------------- fused prep: 5x convert + rope tables + 3x transpose ----------------
// blocks: [0,2048) hq | [2048,2560) kv | [2560,3072) wkv | [3072,5120) Wo | [5120,6656) wkcq |
// [6656,6912) tables | [6912,11008) Wq^T | [11008,12544) W_qr^T | [12544,13056) W_kr^T
__global__ __launch_bounds__(256) void prep_kernel(
    const float* __restrict__ s0, uint16_t* __restrict__ t0, const float* __restrict__ s1,
    uint16_t* __restrict__ t1, const float* __restrict__ s2, uint16_t* __restrict__ t2,
    const float* __restrict__ s3, uint16_t* __restrict__ t3, const float* __restrict__ s4,
    uint16_t* __restrict__ t4, float* __restrict__ cosK, float* __restrict__ sinK,
    float* __restrict__ cosQ, float* __restrict__ sinQ, const float* __restrict__ Wq,
    uint16_t* __restrict__ WqT, const float* __restrict__ W_qr, uint16_t* __restrict__ WqrT,
    const float* __restrict__ W_kr, uint16_t* __restrict__ WkrT) {
  __shared__ float t[32][33];
  int bid = blockIdx.x;
  if (bid >= 6912) {  // transpose segments
    int tb = bid - 6912;
    const float* src;
    uint16_t* dst;
    int R, C, r0, c0;
    if (tb < 4096) {
      src = Wq; dst = WqT; R = 2048; C = 2048;
      r0 = (tb & 63) * 32; c0 = (tb >> 6) * 32;
    } else if (tb < 5632) {
      int b = tb - 4096;
      int z = b / 96, rem = b % 96;
      src = W_qr + (size_t)z * 98304; dst = WqrT + (size_t)z * 98304;
      R = 1536; C = 64;
      r0 = (rem >> 1) * 32; c0 = (rem & 1) * 32;
    } else {
      int b = tb - 5632;
      int z = b / 32, rem = b % 32;
      src = W_kr + (size_t)z * 32768; dst = WkrT + (size_t)z * 32768;
      R = 512; C = 64;
      r0 = (rem >> 1) * 32; c0 = (rem & 1) * 32;
    }
    int tr = threadIdx.x >> 5, tc = threadIdx.x & 31;
#pragma unroll
    for (int i = 0; i < 4; ++i) t[tr + i * 8][tc] = src[(size_t)(r0 + tr + i * 8) * C + c0 + tc];
    __syncthreads();
#pragma unroll
    for (int i = 0; i < 4; ++i)
      dst[(size_t)(c0 + tr + i * 8) * R + r0 + tc] = f2b(t[tc][tr + i * 8]);
    return;
  }
  if (bid >= 6656) {  // rope tables
    const float LOG2E = 1.44269504088896341f;
    int idx = (bid - 6656) * 256 + threadIdx.x;
    int s = idx >> 6, j = idx & 63;
    int i = j & 31;
    float inv = powf(10000.0f, -(float)(2 * i) / 64.0f);
    float ang = (float)s * inv;
    float c = cosf(ang), sn = sinf(ang);
    cosK[idx] = c;
    sinK[idx] = sn;
    cosQ[idx] = c * LOG2E;
    sinQ[idx] = sn * LOG2E;
    return;
  }
  const float* s;
  uint16_t* tt;
  int off;
  if (bid < 2048) { s = s0; tt = t0; off = bid; }
  else if (bid < 2560) { s = s1; tt = t1; off = bid - 2048; }
  else if (bid < 3072) { s = s2; tt = t2; off = bid - 2560; }
  else if (bid < 5120) { s = s3; tt = t3; off = bid - 3072; }
  else { s = s4; tt = t4; off = bid - 5120; }
  int i = off * 256 + threadIdx.x;
  const float4* s4v = (const float4*)s;
  float4 a = s4v[i * 2], b = s4v[i * 2 + 1];
  uint4 v;
  v.x = cvtpk_bf16(a.x, a.y);
  v.y = cvtpk_bf16(a.z, a.w);
  v.z = cvtpk_bf16(b.x, b.y);
  v.w = cvtpk_bf16(b.z, b.w);
  ((uint4*)tt)[i] = v;
}

// ---------------- MFMA GEMM (generic bf16): C = A @ Bt^T, BM x 128 tile, dbuf ----------------
// EPI 0: f32 row-major (z-linear via cZ). SPLITK>1: z = zh*SPLITK+zk, K-offset zk*K.
template <int BM, int EPI, int SPLITK = 1>
__global__ __launch_bounds__(256) void gemm_mfma_kernel(const uint16_t* __restrict__ A,
                                                        const uint16_t* __restrict__ Bt,
                                                        void* __restrict__ Cv, int K, int lda,
                                                        int ldb, int ldc, int aZ, int bZ,
                                                        int cZ) {
  constexpr int MT = BM / 32;
  __shared__ __align__(16) uint16_t As[2][BM * 64];
  __shared__ __align__(16) uint16_t Bs[2][128 * 64];
  int z = blockIdx.z;
  if (SPLITK > 1) {
    int zh = z / SPLITK, zk = z % SPLITK;
    A += (size_t)zh * aZ + (size_t)zk * K;
    Bt += (size_t)zh * bZ + (size_t)zk * K;
  } else {
    A += (size_t)z * aZ;
    Bt += (size_t)z * bZ;
  }
  int m0 = blockIdx.x * BM, n0 = blockIdx.y * 128;
  int tid = threadIdx.x;
  int wave = tid >> 6, lane = tid & 63;
  int wm = wave >> 1, wn = wave & 1;
  int rS = lane >> 3, sl = lane & 7;
  int lr = lane >> 4, lc = lane & 15;

  auto stage = [&](int k0, int buf) {
#pragma unroll
    for (int i = 0; i < MT; ++i) {
      int idx = wave * MT + i;
      int row = idx * 8 + rS;
      GLOAD16(A + (size_t)(m0 + row) * lda + k0 + ((sl ^ (row & 7)) << 3),
              (uint8_t*)As[buf] + idx * 1024);
    }
#pragma unroll
    for (int i = 0; i < 4; ++i) {
      int idx = wave * 4 + i;
      int row = idx * 8 + rS;
      GLOAD16(Bt + (size_t)(n0 + row) * ldb + k0 + ((sl ^ (row & 7)) << 3),
              (uint8_t*)Bs[buf] + idx * 1024);
    }
  };

  f32x4 acc[MT][4] = {};
  stage(0, 0);
  int cur = 0;
  for (int k0 = 0; k0 < K; k0 += 64) {
    __syncthreads();
    if (k0 + 64 < K) stage(k0 + 64, cur ^ 1);
    short8 af[MT][2], bf[4][2];
#pragma unroll
    for (int t = 0; t < MT; ++t)
#pragma unroll
      for (int ks = 0; ks < 2; ++ks) {
        int slot = ks * 4 + lr;
        int ra = wm * (BM / 2) + t * 16 + lc;
        af[t][ks] =
            *(const short8*)((const uint8_t*)As[cur] + ra * 128 + ((slot ^ (ra & 7)) << 4));
      }
#pragma unroll
    for (int t = 0; t < 4; ++t)
#pragma unroll
      for (int ks = 0; ks < 2; ++ks) {
        int slot = ks * 4 + lr;
        int rb = wn * 64 + t * 16 + lc;
        bf[t][ks] =
            *(const short8*)((const uint8_t*)Bs[cur] + rb * 128 + ((slot ^ (rb & 7)) << 4));
      }
    __builtin_amdgcn_s_setprio(1);
#pragma unroll
    for (int mt = 0; mt < MT; ++mt)
#pragma unroll
      for (int nt = 0; nt < 4; ++nt) {
        acc[mt][nt] =
            __builtin_amdgcn_mfma_f32_16x16x32_bf16(af[mt][0], bf[nt][0], acc[mt][nt], 0, 0, 0);
        acc[mt][nt] =
            __builtin_amdgcn_mfma_f32_16x16x32_bf16(af[mt][1], bf[nt][1], acc[mt][nt], 0, 0, 0);
      }
    __builtin_amdgcn_s_setprio(0);
    cur ^= 1;
  }
#pragma unroll
  for (int mt = 0; mt < MT; ++mt)
#pragma unroll
    for (int nt = 0; nt < 4; ++nt)
#pragma unroll
      for (int r = 0; r < 4; ++r) {
        int m = m0 + wm * (BM / 2) + mt * 16 + lr * 4 + r;
        int n = n0 + wn * 64 + nt * 16 + lc;
        float v = acc[mt][nt][r];
        if (EPI == 0)
          ((float*)Cv)[(size_t)z * cZ + (size_t)m * ldc + n] = v;
        else
          ((uint16_t*)Cv)[(size_t)z * cZ + (size_t)m * ldc + n] = f2b(v);
      }
}

// ---------------- out GEMM: bf16 A/B via global_load_lds, bijective XCD swizzle ----------
// grid (32, 16), 256 thr, 64 x 128 tile, dbuf. Each 128-col B-panel's 32 reader blocks land
// on ONE XCD (panel fetched into a single L2 instead of all 8).
__global__ __launch_bounds__(256) void gemm_out_kernel(const uint16_t* __restrict__ A,
                                                       const uint16_t* __restrict__ Bt,
                                                       float* __restrict__ C) {
  __shared__ __align__(16) uint16_t As[2][64 * 64];
  __shared__ __align__(16) uint16_t Bs[2][128 * 64];
  int lin = blockIdx.x + 32 * blockIdx.y;
  int swz = (lin & 7) * 64 + (lin >> 3);  // XCD x gets swz in [x*64, x*64+64): 2 n-panels
  int m0 = (swz & 31) * 64, n0 = (swz >> 5) * 128;
  int tid = threadIdx.x;
  int wave = tid >> 6, lane = tid & 63;
  int wm = wave >> 1, wn = wave & 1;
  int rS = lane >> 3, sl = lane & 7;
  int lr = lane >> 4, lc = lane & 15;

  auto stage = [&](int k0, int buf) {
#pragma unroll
    for (int i = 0; i < 2; ++i) {
      int idx = wave * 2 + i;
      int row = idx * 8 + rS;
      GLOAD16(A + (size_t)(m0 + row) * 2048 + k0 + ((sl ^ (row & 7)) << 3),
              (uint8_t*)As[buf] + idx * 1024);
    }
#pragma unroll
    for (int i = 0; i < 4; ++i) {
      int idx = wave * 4 + i;
      int row = idx * 8 + rS;
      GLOAD16(Bt + (size_t)(n0 + row) * 2048 + k0 + ((sl ^ (row & 7)) << 3),
              (uint8_t*)Bs[buf] + idx * 1024);
    }
  };

  f32x4 acc[2][4] = {};
  stage(0, 0);
  int cur = 0;
  for (int k0 = 0; k0 < 2048; k0 += 64) {
    __syncthreads();
    if (k0 + 64 < 2048) stage(k0 + 64, cur ^ 1);
    short8 af[2][2], bf[4][2];
#pragma unroll
    for (int t = 0; t < 2; ++t)
#pragma unroll
      for (int ks = 0; ks < 2; ++ks) {
        int slot = ks * 4 + lr;
        int ra = wm * 32 + t * 16 + lc;
        af[t][ks] =
            *(const short8*)((const uint8_t*)As[cur] + ra * 128 + ((slot ^ (ra & 7)) << 4));
      }
#pragma unroll
    for (int t = 0; t < 4; ++t)
#pragma unroll
      for (int ks = 0; ks < 2; ++ks) {
        int slot = ks * 4 + lr;
        int rb = wn * 64 + t * 16 + lc;
        bf[t][ks] =
            *(const short8*)((const uint8_t*)Bs[cur] + rb * 128 + ((slot ^ (rb & 7)) << 4));
      }
    __builtin_amdgcn_s_setprio(1);
#pragma unroll
    for (int mt = 0; mt < 2; ++mt)
#pragma unroll
      for (int nt = 0; nt < 4; ++nt) {
        acc[mt][nt] =
            __builtin_amdgcn_mfma_f32_16x16x32_bf16(af[mt][0], bf[nt][0], acc[mt][nt], 0, 0, 0);
        acc[mt][nt] =
            __builtin_amdgcn_mfma_f32_16x16x32_bf16(af[mt][1], bf[nt][1], acc[mt][nt], 0, 0, 0);
      }
    __builtin_amdgcn_s_setprio(0);
    cur ^= 1;
  }
#pragma unroll
  for (int mt = 0; mt < 2; ++mt)
#pragma unroll
    for (int nt = 0; nt < 4; ++nt)
#pragma unroll
      for (int r = 0; r < 4; ++r) {
        int m = m0 + wm * 32 + mt * 16 + lr * 4 + r;
        int n = n0 + wn * 64 + nt * 16 + lc;
        C[(size_t)m * 2048 + n] = acc[mt][nt][r];
      }
}

// ---------------- fold2 fused: A = reduce8(tmp1[head]) in LDS; B = WqT staged ----------------
// grid (1, 16 ntiles, 16 heads), 256 thr. WfoldT[h*64+m][n] = sum_k A[m][k] * WqT[n][h*128+k]
__global__ __launch_bounds__(256) void fold2_kernel(const float* __restrict__ tmp1,
                                                    const uint16_t* __restrict__ WqT,
                                                    uint16_t* __restrict__ WfoldT) {
  __shared__ __align__(16) uint16_t As[2][64 * 64];
  __shared__ __align__(16) uint16_t Bs[2][128 * 64];
  int z = blockIdx.z;
  int n0 = blockIdx.y * 128;
  const uint16_t* Bt = WqT + z * 128;
  int tid = threadIdx.x;
  int wave = tid >> 6, lane = tid & 63;
  int wm = wave >> 1, wn = wave & 1;
  int rS = lane >> 3, sl = lane & 7;
  int lr = lane >> 4, lc = lane & 15;

  // A prefill: sum 8 f32 partials -> bf16, swizzled, into As[0] (k 0..63) and As[1] (k 64..127)
  {
    int row = tid >> 2;
    int kbase = (tid & 3) * 32;
    const float* tp = tmp1 + (size_t)z * 65536 + row * 128;
#pragma unroll
    for (int c = 0; c < 8; ++c) {
      int k4 = kbase + c * 4;
      float4 s = *(const float4*)(tp + k4);
#pragma unroll
      for (int p = 1; p < 8; ++p) {
        float4 sp = *(const float4*)(tp + p * 8192 + k4);
        s.x += sp.x;
        s.y += sp.y;
        s.z += sp.z;
        s.w += sp.w;
      }
      uint32_t lo = cvtpk_bf16(s.x, s.y);
      uint32_t hi = cvtpk_bf16(s.z, s.w);
      int buf = k4 >> 6, kl = k4 & 63;
      int slot = kl >> 3;
      uint32_t addr = row * 128 + ((slot ^ (row & 7)) << 4) + (kl & 7) * 2;
      *(uint32_t*)((uint8_t*)As[buf] + addr) = lo;
      *(uint32_t*)((uint8_t*)As[buf] + addr + 4) = hi;
    }
  }

  auto stageB = [&](int k0, int buf) {
#pragma unroll
    for (int i = 0; i < 4; ++i) {
      int idx = wave * 4 + i;
      int row = idx * 8 + rS;
      GLOAD16(Bt + (size_t)(n0 + row) * 2048 + k0 + ((sl ^ (row & 7)) << 3),
              (uint8_t*)Bs[buf] + idx * 1024);
    }
  };

  f32x4 acc[2][4] = {};
  stageB(0, 0);
  int cur = 0;
  for (int k0 = 0; k0 < 128; k0 += 64) {
    __syncthreads();  // drains gloads AND makes A-prefill ds_writes visible
    if (k0 + 64 < 128) stageB(64, 1);
    short8 af[2][2], bf[4][2];
#pragma unroll
    for (int t = 0; t < 2; ++t)
#pragma unroll
      for (int ks = 0; ks < 2; ++ks) {
        int slot = ks * 4 + lr;
        int ra = wm * 32 + t * 16 + lc;
        af[t][ks] =
            *(const short8*)((const uint8_t*)As[cur] + ra * 128 + ((slot ^ (ra & 7)) << 4));
      }
#pragma unroll
    for (int t = 0; t < 4; ++t)
#pragma unroll
      for (int ks = 0; ks < 2; ++ks) {
        int slot = ks * 4 + lr;
        int rb = wn * 64 + t * 16 + lc;
        bf[t][ks] =
            *(const short8*)((const uint8_t*)Bs[cur] + rb * 128 + ((slot ^ (rb & 7)) << 4));
      }
    __builtin_amdgcn_s_setprio(1);
#pragma unroll
    for (int mt = 0; mt < 2; ++mt)
#pragma unroll
      for (int nt = 0; nt < 4; ++nt) {
        acc[mt][nt] =
            __builtin_amdgcn_mfma_f32_16x16x32_bf16(af[mt][0], bf[nt][0], acc[mt][nt], 0, 0, 0);
        acc[mt][nt] =
            __builtin_amdgcn_mfma_f32_16x16x32_bf16(af[mt][1], bf[nt][1], acc[mt][nt], 0, 0, 0);
      }
    __builtin_amdgcn_s_setprio(0);
    cur ^= 1;
  }
#pragma unroll
  for (int mt = 0; mt < 2; ++mt)
#pragma unroll
    for (int nt = 0; nt < 4; ++nt)
#pragma unroll
      for (int r = 0; r < 4; ++r) {
        int m = wm * 32 + mt * 16 + lr * 4 + r;
        int n = n0 + wn * 64 + nt * 16 + lc;
        WfoldT[(size_t)z * 131072 + (size_t)m * 2048 + n] = f2b(acc[mt][nt][r]);
      }
}

// ---------------- triple GEMM: qr (y<8) | kr (y<16) | VhT (y<32) in one launch ----------------
// grid (32, 32), 256 thr. qr: rope_q(hqb @ WfoldT^T); kr: rope_k(kvb @ WkrT^T);
// VhT: kvb @ wkvb^T in VhT layout. All operands bf16 via global_load_lds.
__global__ __launch_bounds__(256) void gemm_triple_kernel(
    const uint16_t* __restrict__ hqb, const uint16_t* __restrict__ WfoldT,
    uint16_t* __restrict__ qrb, const uint16_t* __restrict__ kvb,
    const uint16_t* __restrict__ WkrT, uint16_t* __restrict__ krb,
    const uint16_t* __restrict__ wkvb, uint16_t* __restrict__ VhT,
    const float* __restrict__ cosQ, const float* __restrict__ sinQ,
    const float* __restrict__ cosK, const float* __restrict__ sinK) {
  __shared__ __align__(16) uint16_t As[2][64 * 64];
  __shared__ __align__(16) uint16_t Bs[2][128 * 64];
  int bx = blockIdx.x, byr = blockIdx.y;
  const uint16_t *A, *Bt;
  uint16_t* Cv;
  const float *rc, *rs;
  int K, lda, ldb, n0, mode;  // mode 0: rope bf16 (ldc=1024); 1: VhT layout
  if (byr < 8) {
    A = hqb; Bt = WfoldT; Cv = qrb; K = 2048; lda = 2048; ldb = 2048;
    n0 = byr * 128; mode = 0; rc = cosQ; rs = sinQ;
  } else if (byr < 16) {
    A = kvb; Bt = WkrT; Cv = krb; K = 512; lda = 512; ldb = 512;
    n0 = (byr - 8) * 128; mode = 0; rc = cosK; rs = sinK;
  } else {
    A = kvb; Bt = wkvb; Cv = VhT; K = 512; lda = 512; ldb = 512;
    n0 = (byr - 16) * 128; mode = 1; rc = nullptr; rs = nullptr;
  }
  int m0 = bx * 64;
  int tid = threadIdx.x;
  int wave = tid >> 6, lane = tid & 63;
  int wm = wave >> 1, wn = wave & 1;
  int rS = lane >> 3, sl = lane & 7;
  int lr = lane >> 4, lc = lane & 15;

  auto stage = [&](int k0, int buf) {
#pragma unroll
    for (int i = 0; i < 2; ++i) {
      int idx = wave * 2 + i;
      int row = idx * 8 + rS;
      GLOAD16(A + (size_t)(m0 + row) * lda + k0 + ((sl ^ (row & 7)) << 3),
              (uint8_t*)As[buf] + idx * 1024);
    }
#pragma unroll
    for (int i = 0; i < 4; ++i) {
      int idx = wave * 4 + i;
      int row = idx * 8 + rS;
      GLOAD16(Bt + (size_t)(n0 + row) * ldb + k0 + ((sl ^ (row & 7)) << 3),
              (uint8_t*)Bs[buf] + idx * 1024);
    }
  };

  f32x4 acc[2][4] = {};
  stage(0, 0);
  int cur = 0;
  for (int k0 = 0; k0 < K; k0 += 64) {
    __syncthreads();
    if (k0 + 64 < K) stage(k0 + 64, cur ^ 1);
    short8 af[2][2], bf[4][2];
#pragma unroll
    for (int t = 0; t < 2; ++t)
#pragma unroll
      for (int ks = 0; ks < 2; ++ks) {
        int slot = ks * 4 + lr;
        int ra = wm * 32 + t * 16 + lc;
        af[t][ks] =
            *(const short8*)((const uint8_t*)As[cur] + ra * 128 + ((slot ^ (ra & 7)) << 4));
      }
#pragma unroll
    for (int t = 0; t < 4; ++t)
#pragma unroll
      for (int ks = 0; ks < 2; ++ks) {
        int slot = ks * 4 + lr;
        int rb = wn * 64 + t * 16 + lc;
        bf[t][ks] =
            *(const short8*)((const uint8_t*)Bs[cur] + rb * 128 + ((slot ^ (rb & 7)) << 4));
      }
    __builtin_amdgcn_s_setprio(1);
#pragma unroll
    for (int mt = 0; mt < 2; ++mt)
#pragma unroll
      for (int nt = 0; nt < 4; ++nt) {
        acc[mt][nt] =
            __builtin_amdgcn_mfma_f32_16x16x32_bf16(af[mt][0], bf[nt][0], acc[mt][nt], 0, 0, 0);
        acc[mt][nt] =
            __builtin_amdgcn_mfma_f32_16x16x32_bf16(af[mt][1], bf[nt][1], acc[mt][nt], 0, 0, 0);
      }
    __builtin_amdgcn_s_setprio(0);
    cur ^= 1;
  }
  if (mode == 0) {
#pragma unroll
    for (int mt = 0; mt < 2; ++mt)
#pragma unroll
      for (int nt = 0; nt < 4; ++nt)
#pragma unroll
        for (int r = 0; r < 4; ++r) {
          int m = m0 + wm * 32 + mt * 16 + lr * 4 + r;
          int n = n0 + wn * 64 + nt * 16 + lc;
          int pos = m & 1023, j = n & 63;
          float x = acc[mt][nt][r];
          float prt = acc[mt][nt ^ 2][r];
          float rot = (nt & 2) ? prt : -prt;
          float v = fmaf(x, rc[pos * 64 + j], rot * rs[pos * 64 + j]);
          Cv[(size_t)m * 1024 + n] = f2b(v);
        }
  } else {
#pragma unroll
    for (int mt = 0; mt < 2; ++mt)
#pragma unroll
      for (int nt = 0; nt < 4; ++nt)
#pragma unroll
        for (int r = 0; r < 4; ++r) {
          int m = m0 + wm * 32 + mt * 16 + lr * 4 + r;
          int n = n0 + wn * 64 + nt * 16 + lc;
          Cv[((size_t)((m >> 10) * 2048 + n)) * 1024 + (m & 1023)] = f2b(acc[mt][nt][r]);
        }
  }
}

// ---------------- MFMA flash attention, swapped QK^T, Q-split 8 waves, FIXED-MAX softmax ----
// grid (bh=32, stile=8), 512 thr = 8 waves; wave owns q-rows s0 + wave*16 .. +15; all waves share
// one dbuf K/V tile (3 gloads/wave), ONE barrier/iter, prefetch-under-compute.
// Softmax uses FIXED max M=8 (exp2 domain; exact by shift-invariance — scores are O(1)).
// Out: ctxlatb bf16 [b*1024+s][2048]
__global__ __launch_bounds__(512, 2) void flash3_kernel(const uint16_t* __restrict__ qrb,
                                                        const uint16_t* __restrict__ krb,
                                                        const uint16_t* __restrict__ VhT,
                                                        uint16_t* __restrict__ ctxlatb) {
  // LDS: Ks[2][8192] @0 | Vs[2][16384] @16384 | Ps[8][2304] @49152  (total 67584 B)
  __shared__ __align__(16) uint8_t lds[67584];
  int bh = blockIdx.x;
  int b = bh >> 4, h = bh & 15;
  int s0 = blockIdx.y * 128;
  int tid = threadIdx.x, wave = tid >> 6, lane = tid & 63;
  int lr = lane >> 4, lc = lane & 15;
  int rS = lane >> 3, sl = lane & 7;

  uint8_t* Ps = lds + 49152 + wave * 2304;

  const uint16_t* qrow = qrb + (size_t)(b * 1024 + s0 + wave * 16 + lc) * 1024 + h * 64;
  short8 qa[2];
  qa[0] = *(const short8*)(qrow + lr * 8);
  qa[1] = *(const short8*)(qrow + 32 + lr * 8);

  float l_run = 0.f;
  f32x4 o[8] = {};

  uint8_t* psW = Ps + lc * 144 + lr * 8;
  const uint8_t* psR = Ps + lc * 144 + lr * 16;

  const uint16_t* krbase = krb + (size_t)(b * 1024) * 1024 + h * 64;
  const uint16_t* vtbase = VhT + (size_t)(b * 2048 + h * 128) * 1024;

  auto stageKV = [&](int l0, int buf) {
#pragma unroll
    for (int i = 0; i < 3; ++i) {
      int g = wave * 3 + i;
      if (g < 8) {
        int row = g * 8 + rS;
        GLOAD16(krbase + (size_t)(l0 + row) * 1024 + ((sl ^ (row & 7)) << 3),
                lds + buf * 8192 + g * 1024);
      } else {
        int v = g - 8;
        int row = v * 8 + rS;
        GLOAD16(vtbase + (size_t)row * 1024 + l0 + ((sl ^ (row & 7)) << 3),
                lds + 16384 + buf * 16384 + v * 1024);
      }
    }
  };

  stageKV(0, 0);
  int cur = 0;
  for (int t = 0; t < 16; ++t) {
    __syncthreads();
    if (t < 15) stageKV((t + 1) * 64, cur ^ 1);
    const uint8_t* Ks = lds + cur * 8192;
    const uint8_t* Vs = lds + 16384 + cur * 16384;

    f32x4 sc[4];
    __builtin_amdgcn_s_setprio(1);
#pragma unroll
    for (int nt = 0; nt < 4; ++nt) {
      int rowk = nt * 16 + lc;
      short8 kb0 = *(const short8*)(Ks + rowk * 128 + ((lr ^ (rowk & 7)) << 4));
      short8 kb1 = *(const short8*)(Ks + rowk * 128 + (((4 + lr) ^ (rowk & 7)) << 4));
      f32x4 z = {};
      z = __builtin_amdgcn_mfma_f32_16x16x32_bf16(kb0, qa[0], z, 0, 0, 0);
      sc[nt] = __builtin_amdgcn_mfma_f32_16x16x32_bf16(kb1, qa[1], z, 0, 0, 0);
    }
    __builtin_amdgcn_s_setprio(0);

    float ps = 0.f;
#pragma unroll
    for (int nt = 0; nt < 4; ++nt) {
#pragma unroll
      for (int rp = 0; rp < 2; ++rp) {
        float p0 = exp2f(sc[nt][rp * 2] - 8.0f);
        float p1 = exp2f(sc[nt][rp * 2 + 1] - 8.0f);
        ps += p0 + p1;
        *(uint32_t*)(psW + nt * 32 + rp * 4) = cvtpk_bf16(p0, p1);
      }
    }
    l_run += ps;

    short8 pa[2];
    pa[0] = *(const short8*)(psR);
    pa[1] = *(const short8*)(psR + 64);
    __builtin_amdgcn_s_setprio(1);
#pragma unroll
    for (int nt = 0; nt < 8; ++nt) {
      int rowv = nt * 16 + lc;
      short8 vb0 = *(const short8*)(Vs + rowv * 128 + ((lr ^ (rowv & 7)) << 4));
      short8 vb1 = *(const short8*)(Vs + rowv * 128 + (((4 + lr) ^ (rowv & 7)) << 4));
      o[nt] = __builtin_amdgcn_mfma_f32_16x16x32_bf16(pa[0], vb0, o[nt], 0, 0, 0);
      o[nt] = __builtin_amdgcn_mfma_f32_16x16x32_bf16(pa[1], vb1, o[nt], 0, 0, 0);
    }
    __builtin_amdgcn_s_setprio(0);
    cur ^= 1;
  }

  l_run += __shfl_xor(l_run, 16);
  l_run += __shfl_xor(l_run, 32);
  float li[4];
#pragma unroll
  for (int r = 0; r < 4; ++r) li[r] = 1.0f / __shfl(l_run, lr * 4 + r);
  uint16_t* orow = ctxlatb + (size_t)(b * 1024 + s0 + wave * 16) * 2048 + h * 128;
#pragma unroll
  for (int nt = 0; nt < 8; ++nt)
#pragma unroll
    for (int r = 0; r < 4; ++r)
      orow[(size_t)(lr * 4 + r) * 2048 + nt * 16 + lc] = f2b(o[nt][r] * li[r]);
}

extern "C" void kernel_launch(void* const* d_in, const int* in_sizes, int n_in,
                              void* d_out, int out_size, void* d_ws, size_t ws_size,
                              hipStream_t stream) {
  const float* hidden_q = (const float*)d_in[0];
  const float* kv_c = (const float*)d_in[1];
  const float* Wq = (const float*)d_in[2];
  const float* w_kc_q = (const float*)d_in[3];
  const float* W_qr = (const float*)d_in[4];
  const float* W_kr = (const float*)d_in[5];
  const float* w_kc_kv = (const float*)d_in[6];
  const float* Wo = (const float*)d_in[7];
  float* out = (float*)d_out;

  const size_t MB = 1024 * 1024;
  uint8_t* base = (uint8_t*)d_ws;
  // --- live through flash ---
  uint16_t* Wob = (uint16_t*)(base + 0 * MB);       // 8 MiB
  uint16_t* qrb = (uint16_t*)(base + 8 * MB);       // 4 MiB [2048][1024] (q pre-scaled log2e)
  uint16_t* krb = (uint16_t*)(base + 12 * MB);      // 4 MiB [2048][1024]
  uint16_t* VhT = (uint16_t*)(base + 16 * MB);      // 8 MiB [b*2048+h*128+kk][1024]
  uint16_t* ctxlatb = (uint16_t*)(base + 24 * MB);  // 8 MiB [b*1024+s][2048]
  // --- prep stage (dead by flash time) ---
  float* cosK = (float*)(base + 32 * MB);
  float* sinK = (float*)(base + 32 * MB + 262144);
  float* cosQ = (float*)(base + 32 * MB + 524288);
  float* sinQ = (float*)(base + 32 * MB + 786432);
  uint16_t* hqb = (uint16_t*)(base + 33 * MB);      // 8 MiB
  uint16_t* kvb = (uint16_t*)(base + 41 * MB);      // 2 MiB
  uint16_t* wkvb = (uint16_t*)(base + 43 * MB);     // 2 MiB
  uint16_t* WqT = (uint16_t*)(base + 45 * MB);      // 8 MiB
  uint16_t* WqrT = (uint16_t*)(base + 53 * MB);     // 3 MiB
  uint16_t* wkcqb = (uint16_t*)(base + 56 * MB);    // 6 MiB
  float* tmp1 = (float*)(base + 62 * MB);           // 4 MiB f32 fold1 partials [16][8][8192]
  uint16_t* WkrT = (uint16_t*)(base + 66 * MB);     // 1 MiB

  // fused prep: 5 converts + rope tables + 3 transposes (13056 blocks)
  prep_kernel<<<dim3(13056), dim3(256), 0, stream>>>(
      hidden_q, hqb, kv_c, kvb, w_kc_kv, wkvb, Wo, Wob, w_kc_q, wkcqb, cosK, sinK, cosQ, sinQ, Wq,
      WqT, (const float*)W_qr, WqrT, (const float*)W_kr, WkrT);
  // fold1 split-K x8: tmp1[h*8+zk] = partial sum over q in [zk*192,(zk+1)*192)
  gemm_mfma_kernel<64, 0, 8><<<dim3(1, 1, 128), dim3(256), 0, stream>>>(
      WqrT, wkcqb, tmp1, 192, 1536, 1536, 128, 98304, 196608, 8192);
  // fold2 (fused 8-partial reduce in A-prefill): WfoldT[h*64+r][d]
  uint16_t* WfoldT = wkcqb;  // overlays wkcqb (dead after fold1)
  fold2_kernel<<<dim3(1, 16, 16), dim3(256), 0, stream>>>(tmp1, WqT, WfoldT);
  // triple GEMM: qr (rope_q) + kr (rope_k) + VhT in one launch (1024 blocks)
  gemm_triple_kernel<<<dim3(32, 32), dim3(256), 0, stream>>>(
      hqb, WfoldT, qrb, kvb, WkrT, krb, wkvb, VhT, cosQ, sinQ, cosK, sinK);
  // fused flash attention (Q-split 8 waves, shared dbuf staging, fixed-max softmax) -> ctxlatb
  flash3_kernel<<<dim3(32, 8), dim3(512), 0, stream>>>(qrb, krb, VhT, ctxlatb);
  // out = ctxlatb @ Wob^T (bf16 via global_load_lds, bijective XCD swizzle)
  gemm_out_kernel<<<dim3(32, 16), dim3(256), 0, stream>>>(ctxlatb, Wob, out);
}

// Round 16
// 131.537 us; speedup vs baseline: 1.3812x; 1.0153x over previous
//
#include <hip/hip_runtime.h>
#include <math.h>
#include <stdint.h>

// Sizes (fixed): B=2, S=L=1024, h=16, k=128, d_c=512, d_cq=1536, r=64, dim_q=2048

typedef __attribute__((ext_vector_type(8))) short short8;
typedef __attribute__((ext_vector_type(4))) float f32x4;

#define GLOAD16(gsrc, ldst)                                                            \
  __builtin_amdgcn_global_load_lds((const __attribute__((address_space(1))) void*)(gsrc), \
                                   (__attribute__((address_space(3))) void*)(ldst), 16, 0, 0)

__device__ inline uint16_t f2b(float x) {  // round-to-nearest-even f32 -> bf16
  uint32_t u = __builtin_bit_cast(uint32_t, x);
  u += 0x7fff + ((u >> 16) & 1);
  return (uint16_t)(u >> 16);
}
__device__ inline uint32_t cvtpk_bf16(float lo, float hi) {  // packs 2 f32 -> 2 bf16 (RNE)
  uint32_t d;
  asm("v_cvt_pk_bf16_f32 %0, %1, %2" : "=v"(d) : "v"(lo), "v"(hi));
  return d;
}

// ---------------- fused prep: 5x convert + rope tables + 3x transpose ----------------
// blocks: [0,2048) hq | [2048,2560) kv | [2560,3072) wkv | [3072,5120) Wo | [5120,6656) wkcq |
// [6656,6912) tables | [6912,11008) Wq^T | [11008,12544) W_qr^T | [12544,13056) W_kr^T
__global__ __launch_bounds__(256) void prep_kernel(
    const float* __restrict__ s0, uint16_t* __restrict__ t0, const float* __restrict__ s1,
    uint16_t* __restrict__ t1, const float* __restrict__ s2, uint16_t* __restrict__ t2,
    const float* __restrict__ s3, uint16_t* __restrict__ t3, const float* __restrict__ s4,
    uint16_t* __restrict__ t4, float* __restrict__ cosK, float* __restrict__ sinK,
    float* __restrict__ cosQ, float* __restrict__ sinQ, const float* __restrict__ Wq,
    uint16_t* __restrict__ WqT, const float* __restrict__ W_qr, uint16_t* __restrict__ WqrT,
    const float* __restrict__ W_kr, uint16_t* __restrict__ WkrT) {
  __shared__ float t[32][33];
  int bid = blockIdx.x;
  if (bid >= 6912) {  // transpose segments
    int tb = bid - 6912;
    const float* src;
    uint16_t* dst;
    int R, C, r0, c0;
    if (tb < 4096) {
      src = Wq; dst = WqT; R = 2048; C = 2048;
      r0 = (tb & 63) * 32; c0 = (tb >> 6) * 32;
    } else if (tb < 5632) {
      int b = tb - 4096;
      int z = b / 96, rem = b % 96;
      src = W_qr + (size_t)z * 98304; dst = WqrT + (size_t)z * 98304;
      R = 1536; C = 64;
      r0 = (rem >> 1) * 32; c0 = (rem & 1) * 32;
    } else {
      int b = tb - 5632;
      int z = b / 32, rem = b % 32;
      src = W_kr + (size_t)z * 32768; dst = WkrT + (size_t)z * 32768;
      R = 512; C = 64;
      r0 = (rem >> 1) * 32; c0 = (rem & 1) * 32;
    }
    int tr = threadIdx.x >> 5, tc = threadIdx.x & 31;
#pragma unroll
    for (int i = 0; i < 4; ++i) t[tr + i * 8][tc] = src[(size_t)(r0 + tr + i * 8) * C + c0 + tc];
    __syncthreads();
#pragma unroll
    for (int i = 0; i < 4; ++i)
      dst[(size_t)(c0 + tr + i * 8) * R + r0 + tc] = f2b(t[tc][tr + i * 8]);
    return;
  }
  if (bid >= 6656) {  // rope tables
    const float LOG2E = 1.44269504088896341f;
    int idx = (bid - 6656) * 256 + threadIdx.x;
    int s = idx >> 6, j = idx & 63;
    int i = j & 31;
    float inv = powf(10000.0f, -(float)(2 * i) / 64.0f);
    float ang = (float)s * inv;
    float c = cosf(ang), sn = sinf(ang);
    cosK[idx] = c;
    sinK[idx] = sn;
    cosQ[idx] = c * LOG2E;
    sinQ[idx] = sn * LOG2E;
    return;
  }
  const float* s;
  uint16_t* tt;
  int off;
  if (bid < 2048) { s = s0; tt = t0; off = bid; }
  else if (bid < 2560) { s = s1; tt = t1; off = bid - 2048; }
  else if (bid < 3072) { s = s2; tt = t2; off = bid - 2560; }
  else if (bid < 5120) { s = s3; tt = t3; off = bid - 3072; }
  else { s = s4; tt = t4; off = bid - 5120; }
  int i = off * 256 + threadIdx.x;
  const float4* s4v = (const float4*)s;
  float4 a = s4v[i * 2], b = s4v[i * 2 + 1];
  uint4 v;
  v.x = cvtpk_bf16(a.x, a.y);
  v.y = cvtpk_bf16(a.z, a.w);
  v.z = cvtpk_bf16(b.x, b.y);
  v.w = cvtpk_bf16(b.z, b.w);
  ((uint4*)tt)[i] = v;
}

// ---------------- MFMA GEMM (generic bf16): C = A @ Bt^T, BM x 128 tile, dbuf ----------------
// EPI 0: f32 row-major (z-linear via cZ). SPLITK>1: z = zh*SPLITK+zk, K-offset zk*K.
template <int BM, int EPI, int SPLITK = 1>
__global__ __launch_bounds__(256) void gemm_mfma_kernel(const uint16_t* __restrict__ A,
                                                        const uint16_t* __restrict__ Bt,
                                                        void* __restrict__ Cv, int K, int lda,
                                                        int ldb, int ldc, int aZ, int bZ,
                                                        int cZ) {
  constexpr int MT = BM / 32;
  __shared__ __align__(16) uint16_t As[2][BM * 64];
  __shared__ __align__(16) uint16_t Bs[2][128 * 64];
  int z = blockIdx.z;
  if (SPLITK > 1) {
    int zh = z / SPLITK, zk = z % SPLITK;
    A += (size_t)zh * aZ + (size_t)zk * K;
    Bt += (size_t)zh * bZ + (size_t)zk * K;
  } else {
    A += (size_t)z * aZ;
    Bt += (size_t)z * bZ;
  }
  int m0 = blockIdx.x * BM, n0 = blockIdx.y * 128;
  int tid = threadIdx.x;
  int wave = tid >> 6, lane = tid & 63;
  int wm = wave >> 1, wn = wave & 1;
  int rS = lane >> 3, sl = lane & 7;
  int lr = lane >> 4, lc = lane & 15;

  auto stage = [&](int k0, int buf) {
#pragma unroll
    for (int i = 0; i < MT; ++i) {
      int idx = wave * MT + i;
      int row = idx * 8 + rS;
      GLOAD16(A + (size_t)(m0 + row) * lda + k0 + ((sl ^ (row & 7)) << 3),
              (uint8_t*)As[buf] + idx * 1024);
    }
#pragma unroll
    for (int i = 0; i < 4; ++i) {
      int idx = wave * 4 + i;
      int row = idx * 8 + rS;
      GLOAD16(Bt + (size_t)(n0 + row) * ldb + k0 + ((sl ^ (row & 7)) << 3),
              (uint8_t*)Bs[buf] + idx * 1024);
    }
  };

  f32x4 acc[MT][4] = {};
  stage(0, 0);
  int cur = 0;
  for (int k0 = 0; k0 < K; k0 += 64) {
    __syncthreads();
    if (k0 + 64 < K) stage(k0 + 64, cur ^ 1);
    short8 af[MT][2], bf[4][2];
#pragma unroll
    for (int t = 0; t < MT; ++t)
#pragma unroll
      for (int ks = 0; ks < 2; ++ks) {
        int slot = ks * 4 + lr;
        int ra = wm * (BM / 2) + t * 16 + lc;
        af[t][ks] =
            *(const short8*)((const uint8_t*)As[cur] + ra * 128 + ((slot ^ (ra & 7)) << 4));
      }
#pragma unroll
    for (int t = 0; t < 4; ++t)
#pragma unroll
      for (int ks = 0; ks < 2; ++ks) {
        int slot = ks * 4 + lr;
        int rb = wn * 64 + t * 16 + lc;
        bf[t][ks] =
            *(const short8*)((const uint8_t*)Bs[cur] + rb * 128 + ((slot ^ (rb & 7)) << 4));
      }
    __builtin_amdgcn_s_setprio(1);
#pragma unroll
    for (int mt = 0; mt < MT; ++mt)
#pragma unroll
      for (int nt = 0; nt < 4; ++nt) {
        acc[mt][nt] =
            __builtin_amdgcn_mfma_f32_16x16x32_bf16(af[mt][0], bf[nt][0], acc[mt][nt], 0, 0, 0);
        acc[mt][nt] =
            __builtin_amdgcn_mfma_f32_16x16x32_bf16(af[mt][1], bf[nt][1], acc[mt][nt], 0, 0, 0);
      }
    __builtin_amdgcn_s_setprio(0);
    cur ^= 1;
  }
#pragma unroll
  for (int mt = 0; mt < MT; ++mt)
#pragma unroll
    for (int nt = 0; nt < 4; ++nt)
#pragma unroll
      for (int r = 0; r < 4; ++r) {
        int m = m0 + wm * (BM / 2) + mt * 16 + lr * 4 + r;
        int n = n0 + wn * 64 + nt * 16 + lc;
        float v = acc[mt][nt][r];
        if (EPI == 0)
          ((float*)Cv)[(size_t)z * cZ + (size_t)m * ldc + n] = v;
        else
          ((uint16_t*)Cv)[(size_t)z * cZ + (size_t)m * ldc + n] = f2b(v);
      }
}

// ---------------- fold2 fused: A = reduce4(tmp1[head]) in LDS; B = WqT staged ----------------
// grid (1, 16 ntiles, 16 heads), 256 thr. WfoldT[h*64+m][n] = sum_k A[m][k] * WqT[n][h*128+k]
__global__ __launch_bounds__(256) void fold2_kernel(const float* __restrict__ tmp1,
                                                    const uint16_t* __restrict__ WqT,
                                                    uint16_t* __restrict__ WfoldT) {
  __shared__ __align__(16) uint16_t As[2][64 * 64];
  __shared__ __align__(16) uint16_t Bs[2][128 * 64];
  int z = blockIdx.z;
  int n0 = blockIdx.y * 128;
  const uint16_t* Bt = WqT + z * 128;
  int tid = threadIdx.x;
  int wave = tid >> 6, lane = tid & 63;
  int wm = wave >> 1, wn = wave & 1;
  int rS = lane >> 3, sl = lane & 7;
  int lr = lane >> 4, lc = lane & 15;

  // A prefill: sum 4 f32 partials -> bf16, swizzled, into As[0] (k 0..63) and As[1] (k 64..127)
  {
    int row = tid >> 2;
    int kbase = (tid & 3) * 32;
    const float* tp = tmp1 + (size_t)z * 32768 + row * 128;
#pragma unroll
    for (int c = 0; c < 8; ++c) {
      int k4 = kbase + c * 4;
      float4 s = *(const float4*)(tp + k4);
      float4 s1 = *(const float4*)(tp + 8192 + k4);
      float4 s2 = *(const float4*)(tp + 16384 + k4);
      float4 s3 = *(const float4*)(tp + 24576 + k4);
      s.x = ((s.x + s1.x) + s2.x) + s3.x;
      s.y = ((s.y + s1.y) + s2.y) + s3.y;
      s.z = ((s.z + s1.z) + s2.z) + s3.z;
      s.w = ((s.w + s1.w) + s2.w) + s3.w;
      uint32_t lo = cvtpk_bf16(s.x, s.y);
      uint32_t hi = cvtpk_bf16(s.z, s.w);
      int buf = k4 >> 6, kl = k4 & 63;
      int slot = kl >> 3;
      uint32_t addr = row * 128 + ((slot ^ (row & 7)) << 4) + (kl & 7) * 2;
      *(uint32_t*)((uint8_t*)As[buf] + addr) = lo;
      *(uint32_t*)((uint8_t*)As[buf] + addr + 4) = hi;
    }
  }

  auto stageB = [&](int k0, int buf) {
#pragma unroll
    for (int i = 0; i < 4; ++i) {
      int idx = wave * 4 + i;
      int row = idx * 8 + rS;
      GLOAD16(Bt + (size_t)(n0 + row) * 2048 + k0 + ((sl ^ (row & 7)) << 3),
              (uint8_t*)Bs[buf] + idx * 1024);
    }
  };

  f32x4 acc[2][4] = {};
  stageB(0, 0);
  int cur = 0;
  for (int k0 = 0; k0 < 128; k0 += 64) {
    __syncthreads();  // drains gloads AND makes A-prefill ds_writes visible
    if (k0 + 64 < 128) stageB(64, 1);
    short8 af[2][2], bf[4][2];
#pragma unroll
    for (int t = 0; t < 2; ++t)
#pragma unroll
      for (int ks = 0; ks < 2; ++ks) {
        int slot = ks * 4 + lr;
        int ra = wm * 32 + t * 16 + lc;
        af[t][ks] =
            *(const short8*)((const uint8_t*)As[cur] + ra * 128 + ((slot ^ (ra & 7)) << 4));
      }
#pragma unroll
    for (int t = 0; t < 4; ++t)
#pragma unroll
      for (int ks = 0; ks < 2; ++ks) {
        int slot = ks * 4 + lr;
        int rb = wn * 64 + t * 16 + lc;
        bf[t][ks] =
            *(const short8*)((const uint8_t*)Bs[cur] + rb * 128 + ((slot ^ (rb & 7)) << 4));
      }
    __builtin_amdgcn_s_setprio(1);
#pragma unroll
    for (int mt = 0; mt < 2; ++mt)
#pragma unroll
      for (int nt = 0; nt < 4; ++nt) {
        acc[mt][nt] =
            __builtin_amdgcn_mfma_f32_16x16x32_bf16(af[mt][0], bf[nt][0], acc[mt][nt], 0, 0, 0);
        acc[mt][nt] =
            __builtin_amdgcn_mfma_f32_16x16x32_bf16(af[mt][1], bf[nt][1], acc[mt][nt], 0, 0, 0);
      }
    __builtin_amdgcn_s_setprio(0);
    cur ^= 1;
  }
#pragma unroll
  for (int mt = 0; mt < 2; ++mt)
#pragma unroll
    for (int nt = 0; nt < 4; ++nt)
#pragma unroll
      for (int r = 0; r < 4; ++r) {
        int m = wm * 32 + mt * 16 + lr * 4 + r;
        int n = n0 + wn * 64 + nt * 16 + lc;
        WfoldT[(size_t)z * 131072 + (size_t)m * 2048 + n] = f2b(acc[mt][nt][r]);
      }
}

// ---------------- triple GEMM: qr (y<8) | kr (y<16) | VhT (y<32) in one launch ----------------
// grid (32, 32), 256 thr. qr: rope_q(hqb @ WfoldT^T); kr: rope_k(kvb @ WkrT^T);
// VhT: kvb @ wkvb^T in VhT layout. All operands bf16 via global_load_lds.
__global__ __launch_bounds__(256) void gemm_triple_kernel(
    const uint16_t* __restrict__ hqb, const uint16_t* __restrict__ WfoldT,
    uint16_t* __restrict__ qrb, const uint16_t* __restrict__ kvb,
    const uint16_t* __restrict__ WkrT, uint16_t* __restrict__ krb,
    const uint16_t* __restrict__ wkvb, uint16_t* __restrict__ VhT,
    const float* __restrict__ cosQ, const float* __restrict__ sinQ,
    const float* __restrict__ cosK, const float* __restrict__ sinK) {
  __shared__ __align__(16) uint16_t As[2][64 * 64];
  __shared__ __align__(16) uint16_t Bs[2][128 * 64];
  int bx = blockIdx.x, byr = blockIdx.y;
  const uint16_t *A, *Bt;
  uint16_t* Cv;
  const float *rc, *rs;
  int K, lda, ldb, n0, mode;  // mode 0: rope bf16 (ldc=1024); 1: VhT layout
  if (byr < 8) {
    A = hqb; Bt = WfoldT; Cv = qrb; K = 2048; lda = 2048; ldb = 2048;
    n0 = byr * 128; mode = 0; rc = cosQ; rs = sinQ;
  } else if (byr < 16) {
    A = kvb; Bt = WkrT; Cv = krb; K = 512; lda = 512; ldb = 512;
    n0 = (byr - 8) * 128; mode = 0; rc = cosK; rs = sinK;
  } else {
    A = kvb; Bt = wkvb; Cv = VhT; K = 512; lda = 512; ldb = 512;
    n0 = (byr - 16) * 128; mode = 1; rc = nullptr; rs = nullptr;
  }
  int m0 = bx * 64;
  int tid = threadIdx.x;
  int wave = tid >> 6, lane = tid & 63;
  int wm = wave >> 1, wn = wave & 1;
  int rS = lane >> 3, sl = lane & 7;
  int lr = lane >> 4, lc = lane & 15;

  auto stage = [&](int k0, int buf) {
#pragma unroll
    for (int i = 0; i < 2; ++i) {
      int idx = wave * 2 + i;
      int row = idx * 8 + rS;
      GLOAD16(A + (size_t)(m0 + row) * lda + k0 + ((sl ^ (row & 7)) << 3),
              (uint8_t*)As[buf] + idx * 1024);
    }
#pragma unroll
    for (int i = 0; i < 4; ++i) {
      int idx = wave * 4 + i;
      int row = idx * 8 + rS;
      GLOAD16(Bt + (size_t)(n0 + row) * ldb + k0 + ((sl ^ (row & 7)) << 3),
              (uint8_t*)Bs[buf] + idx * 1024);
    }
  };

  f32x4 acc[2][4] = {};
  stage(0, 0);
  int cur = 0;
  for (int k0 = 0; k0 < K; k0 += 64) {
    __syncthreads();
    if (k0 + 64 < K) stage(k0 + 64, cur ^ 1);
    short8 af[2][2], bf[4][2];
#pragma unroll
    for (int t = 0; t < 2; ++t)
#pragma unroll
      for (int ks = 0; ks < 2; ++ks) {
        int slot = ks * 4 + lr;
        int ra = wm * 32 + t * 16 + lc;
        af[t][ks] =
            *(const short8*)((const uint8_t*)As[cur] + ra * 128 + ((slot ^ (ra & 7)) << 4));
      }
#pragma unroll
    for (int t = 0; t < 4; ++t)
#pragma unroll
      for (int ks = 0; ks < 2; ++ks) {
        int slot = ks * 4 + lr;
        int rb = wn * 64 + t * 16 + lc;
        bf[t][ks] =
            *(const short8*)((const uint8_t*)Bs[cur] + rb * 128 + ((slot ^ (rb & 7)) << 4));
      }
    __builtin_amdgcn_s_setprio(1);
#pragma unroll
    for (int mt = 0; mt < 2; ++mt)
#pragma unroll
      for (int nt = 0; nt < 4; ++nt) {
        acc[mt][nt] =
            __builtin_amdgcn_mfma_f32_16x16x32_bf16(af[mt][0], bf[nt][0], acc[mt][nt], 0, 0, 0);
        acc[mt][nt] =
            __builtin_amdgcn_mfma_f32_16x16x32_bf16(af[mt][1], bf[nt][1], acc[mt][nt], 0, 0, 0);
      }
    __builtin_amdgcn_s_setprio(0);
    cur ^= 1;
  }
  if (mode == 0) {
#pragma unroll
    for (int mt = 0; mt < 2; ++mt)
#pragma unroll
      for (int nt = 0; nt < 4; ++nt)
#pragma unroll
        for (int r = 0; r < 4; ++r) {
          int m = m0 + wm * 32 + mt * 16 + lr * 4 + r;
          int n = n0 + wn * 64 + nt * 16 + lc;
          int pos = m & 1023, j = n & 63;
          float x = acc[mt][nt][r];
          float prt = acc[mt][nt ^ 2][r];
          float rot = (nt & 2) ? prt : -prt;
          float v = fmaf(x, rc[pos * 64 + j], rot * rs[pos * 64 + j]);
          Cv[(size_t)m * 1024 + n] = f2b(v);
        }
  } else {
#pragma unroll
    for (int mt = 0; mt < 2; ++mt)
#pragma unroll
      for (int nt = 0; nt < 4; ++nt)
#pragma unroll
        for (int r = 0; r < 4; ++r) {
          int m = m0 + wm * 32 + mt * 16 + lr * 4 + r;
          int n = n0 + wn * 64 + nt * 16 + lc;
          Cv[((size_t)((m >> 10) * 2048 + n)) * 1024 + (m & 1023)] = f2b(acc[mt][nt][r]);
        }
  }
}

// ---------------- MFMA flash attention: 4-wave blocks, 2 blocks/CU ----------------
// grid (bh=32, stile=16), 256 thr = 4 waves; wave owns q-rows s0 + wave*16 .. +15 (s0 = by*64);
// all waves share one dbuf K/V tile (6 gloads/wave), ONE barrier/iter, prefetch-under-compute.
// 2 blocks co-resident per CU stagger their barriers (implicit overlap).
// Fixed-max softmax (exp2 domain, M=8; exact by shift-invariance — scores are O(1)).
// Out: ctxlatb bf16 [b*1024+s][2048]
__global__ __launch_bounds__(256, 2) void flash3_kernel(const uint16_t* __restrict__ qrb,
                                                        const uint16_t* __restrict__ krb,
                                                        const uint16_t* __restrict__ VhT,
                                                        uint16_t* __restrict__ ctxlatb) {
  // LDS: Ks[2][8192] @0 | Vs[2][16384] @16384 | Ps[4][2304] @49152  (total 58368 B)
  __shared__ __align__(16) uint8_t lds[58368];
  int bh = blockIdx.x;
  int b = bh >> 4, h = bh & 15;
  int s0 = blockIdx.y * 64;
  int tid = threadIdx.x, wave = tid >> 6, lane = tid & 63;
  int lr = lane >> 4, lc = lane & 15;
  int rS = lane >> 3, sl = lane & 7;

  uint8_t* Ps = lds + 49152 + wave * 2304;

  const uint16_t* qrow = qrb + (size_t)(b * 1024 + s0 + wave * 16 + lc) * 1024 + h * 64;
  short8 qa[2];
  qa[0] = *(const short8*)(qrow + lr * 8);
  qa[1] = *(const short8*)(qrow + 32 + lr * 8);

  float l_run = 0.f;
  f32x4 o[8] = {};

  uint8_t* psW = Ps + lc * 144 + lr * 8;
  const uint8_t* psR = Ps + lc * 144 + lr * 16;

  const uint16_t* krbase = krb + (size_t)(b * 1024) * 1024 + h * 64;
  const uint16_t* vtbase = VhT + (size_t)(b * 2048 + h * 128) * 1024;

  // cooperative staging: 24 x 1KB gloads (K: 8, V: 16) split 6 per wave
  auto stageKV = [&](int l0, int buf) {
#pragma unroll
    for (int i = 0; i < 6; ++i) {
      int g = wave * 6 + i;
      if (g < 8) {
        int row = g * 8 + rS;
        GLOAD16(krbase + (size_t)(l0 + row) * 1024 + ((sl ^ (row & 7)) << 3),
                lds + buf * 8192 + g * 1024);
      } else {
        int v = g - 8;
        int row = v * 8 + rS;
        GLOAD16(vtbase + (size_t)row * 1024 + l0 + ((sl ^ (row & 7)) << 3),
                lds + 16384 + buf * 16384 + v * 1024);
      }
    }
  };

  stageKV(0, 0);
  int cur = 0;
  for (int t = 0; t < 16; ++t) {
    __syncthreads();
    if (t < 15) stageKV((t + 1) * 64, cur ^ 1);
    const uint8_t* Ks = lds + cur * 8192;
    const uint8_t* Vs = lds + 16384 + cur * 16384;

    f32x4 sc[4];
    __builtin_amdgcn_s_setprio(1);
#pragma unroll
    for (int nt = 0; nt < 4; ++nt) {
      int rowk = nt * 16 + lc;
      short8 kb0 = *(const short8*)(Ks + rowk * 128 + ((lr ^ (rowk & 7)) << 4));
      short8 kb1 = *(const short8*)(Ks + rowk * 128 + (((4 + lr) ^ (rowk & 7)) << 4));
      f32x4 z = {};
      z = __builtin_amdgcn_mfma_f32_16x16x32_bf16(kb0, qa[0], z, 0, 0, 0);
      sc[nt] = __builtin_amdgcn_mfma_f32_16x16x32_bf16(kb1, qa[1], z, 0, 0, 0);
    }
    __builtin_amdgcn_s_setprio(0);

    float ps = 0.f;
#pragma unroll
    for (int nt = 0; nt < 4; ++nt) {
#pragma unroll
      for (int rp = 0; rp < 2; ++rp) {
        float p0 = exp2f(sc[nt][rp * 2] - 8.0f);
        float p1 = exp2f(sc[nt][rp * 2 + 1] - 8.0f);
        ps += p0 + p1;
        *(uint32_t*)(psW + nt * 32 + rp * 4) = cvtpk_bf16(p0, p1);
      }
    }
    l_run += ps;

    short8 pa[2];
    pa[0] = *(const short8*)(psR);
    pa[1] = *(const short8*)(psR + 64);
    __builtin_amdgcn_s_setprio(1);
#pragma unroll
    for (int nt = 0; nt < 8; ++nt) {
      int rowv = nt * 16 + lc;
      short8 vb0 = *(const short8*)(Vs + rowv * 128 + ((lr ^ (rowv & 7)) << 4));
      short8 vb1 = *(const short8*)(Vs + rowv * 128 + (((4 + lr) ^ (rowv & 7)) << 4));
      o[nt] = __builtin_amdgcn_mfma_f32_16x16x32_bf16(pa[0], vb0, o[nt], 0, 0, 0);
      o[nt] = __builtin_amdgcn_mfma_f32_16x16x32_bf16(pa[1], vb1, o[nt], 0, 0, 0);
    }
    __builtin_amdgcn_s_setprio(0);
    cur ^= 1;
  }

  l_run += __shfl_xor(l_run, 16);
  l_run += __shfl_xor(l_run, 32);
  float li[4];
#pragma unroll
  for (int r = 0; r < 4; ++r) li[r] = 1.0f / __shfl(l_run, lr * 4 + r);
  uint16_t* orow = ctxlatb + (size_t)(b * 1024 + s0 + wave * 16) * 2048 + h * 128;
#pragma unroll
  for (int nt = 0; nt < 8; ++nt)
#pragma unroll
    for (int r = 0; r < 4; ++r)
      orow[(size_t)(lr * 4 + r) * 2048 + nt * 16 + lc] = f2b(o[nt][r] * li[r]);
}

extern "C" void kernel_launch(void* const* d_in, const int* in_sizes, int n_in,
                              void* d_out, int out_size, void* d_ws, size_t ws_size,
                              hipStream_t stream) {
  const float* hidden_q = (const float*)d_in[0];
  const float* kv_c = (const float*)d_in[1];
  const float* Wq = (const float*)d_in[2];
  const float* w_kc_q = (const float*)d_in[3];
  const float* W_qr = (const float*)d_in[4];
  const float* W_kr = (const float*)d_in[5];
  const float* w_kc_kv = (const float*)d_in[6];
  const float* Wo = (const float*)d_in[7];
  float* out = (float*)d_out;

  const size_t MB = 1024 * 1024;
  uint8_t* base = (uint8_t*)d_ws;
  // --- live through flash ---
  uint16_t* Wob = (uint16_t*)(base + 0 * MB);       // 8 MiB
  uint16_t* qrb = (uint16_t*)(base + 8 * MB);       // 4 MiB [2048][1024] (q pre-scaled log2e)
  uint16_t* krb = (uint16_t*)(base + 12 * MB);      // 4 MiB [2048][1024]
  uint16_t* VhT = (uint16_t*)(base + 16 * MB);      // 8 MiB [b*2048+h*128+kk][1024]
  uint16_t* ctxlatb = (uint16_t*)(base + 24 * MB);  // 8 MiB [b*1024+s][2048]
  // --- prep stage (dead by flash time) ---
  float* cosK = (float*)(base + 32 * MB);
  float* sinK = (float*)(base + 32 * MB + 262144);
  float* cosQ = (float*)(base + 32 * MB + 524288);
  float* sinQ = (float*)(base + 32 * MB + 786432);
  uint16_t* hqb = (uint16_t*)(base + 33 * MB);      // 8 MiB
  uint16_t* kvb = (uint16_t*)(base + 41 * MB);      // 2 MiB
  uint16_t* wkvb = (uint16_t*)(base + 43 * MB);     // 2 MiB
  uint16_t* WqT = (uint16_t*)(base + 45 * MB);      // 8 MiB
  uint16_t* WqrT = (uint16_t*)(base + 53 * MB);     // 3 MiB
  uint16_t* wkcqb = (uint16_t*)(base + 56 * MB);    // 6 MiB
  float* tmp1 = (float*)(base + 62 * MB);           // 2 MiB f32 fold1 partials [16][4][8192]
  uint16_t* WkrT = (uint16_t*)(base + 64 * MB + 262144);  // 1 MiB

  // fused prep: 5 converts + rope tables + 3 transposes (13056 blocks)
  prep_kernel<<<dim3(13056), dim3(256), 0, stream>>>(
      hidden_q, hqb, kv_c, kvb, w_kc_kv, wkvb, Wo, Wob, w_kc_q, wkcqb, cosK, sinK, cosQ, sinQ, Wq,
      WqT, (const float*)W_qr, WqrT, (const float*)W_kr, WkrT);
  // fold1 split-K x4: tmp1[h*4+zk] = partial sum over q in [zk*384,(zk+1)*384)
  gemm_mfma_kernel<64, 0, 4><<<dim3(1, 1, 64), dim3(256), 0, stream>>>(
      WqrT, wkcqb, tmp1, 384, 1536, 1536, 128, 98304, 196608, 8192);
  // fold2 (fused 4-partial reduce in A-prefill): WfoldT[h*64+r][d]
  uint16_t* WfoldT = wkcqb;  // overlays wkcqb (dead after fold1)
  fold2_kernel<<<dim3(1, 16, 16), dim3(256), 0, stream>>>(tmp1, WqT, WfoldT);
  // triple GEMM: qr (rope_q) + kr (rope_k) + VhT in one launch (1024 blocks)
  gemm_triple_kernel<<<dim3(32, 32), dim3(256), 0, stream>>>(
      hqb, WfoldT, qrb, kvb, WkrT, krb, wkvb, VhT, cosQ, sinQ, cosK, sinK);
  // fused flash attention (4-wave blocks, 2/CU, fixed-max softmax) -> ctxlatb
  flash3_kernel<<<dim3(32, 16), dim3(256), 0, stream>>>(qrb, krb, VhT, ctxlatb);
  // out = ctxlatb @ Wob^T  [2048][2048] f32
  gemm_mfma_kernel<64, 0><<<dim3(32, 16), dim3(256), 0, stream>>>(ctxlatb, Wob, out, 2048, 2048,
                                                                  2048, 2048, 0, 0, 0);
}

// Round 17
// 128.552 us; speedup vs baseline: 1.4132x; 1.0232x over previous
//
#include <hip/hip_runtime.h>
#include <math.h>
#include <stdint.h>

// Sizes (fixed): B=2, S=L=1024, h=16, k=128, d_c=512, d_cq=1536, r=64, dim_q=2048

typedef __attribute__((ext_vector_type(8))) short short8;
typedef __attribute__((ext_vector_type(4))) float f32x4;

#define GLOAD16(gsrc, ldst)                                                            \
  __builtin_amdgcn_global_load_lds((const __attribute__((address_space(1))) void*)(gsrc), \
                                   (__attribute__((address_space(3))) void*)(ldst), 16, 0, 0)

__device__ inline uint16_t f2b(float x) {  // round-to-nearest-even f32 -> bf16
  uint32_t u = __builtin_bit_cast(uint32_t, x);
  u += 0x7fff + ((u >> 16) & 1);
  return (uint16_t)(u >> 16);
}
__device__ inline uint32_t cvtpk_bf16(float lo, float hi) {  // packs 2 f32 -> 2 bf16 (RNE)
  uint32_t d;
  asm("v_cvt_pk_bf16_f32 %0, %1, %2" : "=v"(d) : "v"(lo), "v"(hi));
  return d;
}

// ---------------- fused prep: 5x convert + rope tables + 3x transpose ----------------
// blocks: [0,2048) hq | [2048,2560) kv | [2560,3072) wkv | [3072,5120) Wo | [5120,6656) wkcq |
// [6656,6912) tables | [6912,11008) Wq^T | [11008,12544) W_qr^T | [12544,13056) W_kr^T
__global__ __launch_bounds__(256) void prep_kernel(
    const float* __restrict__ s0, uint16_t* __restrict__ t0, const float* __restrict__ s1,
    uint16_t* __restrict__ t1, const float* __restrict__ s2, uint16_t* __restrict__ t2,
    const float* __restrict__ s3, uint16_t* __restrict__ t3, const float* __restrict__ s4,
    uint16_t* __restrict__ t4, float* __restrict__ cosK, float* __restrict__ sinK,
    float* __restrict__ cosQ, float* __restrict__ sinQ, const float* __restrict__ Wq,
    uint16_t* __restrict__ WqT, const float* __restrict__ W_qr, uint16_t* __restrict__ WqrT,
    const float* __restrict__ W_kr, uint16_t* __restrict__ WkrT) {
  __shared__ float t[32][33];
  int bid = blockIdx.x;
  if (bid >= 6912) {  // transpose segments
    int tb = bid - 6912;
    const float* src;
    uint16_t* dst;
    int R, C, r0, c0;
    if (tb < 4096) {
      src = Wq; dst = WqT; R = 2048; C = 2048;
      r0 = (tb & 63) * 32; c0 = (tb >> 6) * 32;
    } else if (tb < 5632) {
      int b = tb - 4096;
      int z = b / 96, rem = b % 96;
      src = W_qr + (size_t)z * 98304; dst = WqrT + (size_t)z * 98304;
      R = 1536; C = 64;
      r0 = (rem >> 1) * 32; c0 = (rem & 1) * 32;
    } else {
      int b = tb - 5632;
      int z = b / 32, rem = b % 32;
      src = W_kr + (size_t)z * 32768; dst = WkrT + (size_t)z * 32768;
      R = 512; C = 64;
      r0 = (rem >> 1) * 32; c0 = (rem & 1) * 32;
    }
    int tr = threadIdx.x >> 5, tc = threadIdx.x & 31;
#pragma unroll
    for (int i = 0; i < 4; ++i) t[tr + i * 8][tc] = src[(size_t)(r0 + tr + i * 8) * C + c0 + tc];
    __syncthreads();
#pragma unroll
    for (int i = 0; i < 4; ++i)
      dst[(size_t)(c0 + tr + i * 8) * R + r0 + tc] = f2b(t[tc][tr + i * 8]);
    return;
  }
  if (bid >= 6656) {  // rope tables
    const float LOG2E = 1.44269504088896341f;
    int idx = (bid - 6656) * 256 + threadIdx.x;
    int s = idx >> 6, j = idx & 63;
    int i = j & 31;
    float inv = powf(10000.0f, -(float)(2 * i) / 64.0f);
    float ang = (float)s * inv;
    float c = cosf(ang), sn = sinf(ang);
    cosK[idx] = c;
    sinK[idx] = sn;
    cosQ[idx] = c * LOG2E;
    sinQ[idx] = sn * LOG2E;
    return;
  }
  const float* s;
  uint16_t* tt;
  int off;
  if (bid < 2048) { s = s0; tt = t0; off = bid; }
  else if (bid < 2560) { s = s1; tt = t1; off = bid - 2048; }
  else if (bid < 3072) { s = s2; tt = t2; off = bid - 2560; }
  else if (bid < 5120) { s = s3; tt = t3; off = bid - 3072; }
  else { s = s4; tt = t4; off = bid - 5120; }
  int i = off * 256 + threadIdx.x;
  const float4* s4v = (const float4*)s;
  float4 a = s4v[i * 2], b = s4v[i * 2 + 1];
  uint4 v;
  v.x = cvtpk_bf16(a.x, a.y);
  v.y = cvtpk_bf16(a.z, a.w);
  v.z = cvtpk_bf16(b.x, b.y);
  v.w = cvtpk_bf16(b.z, b.w);
  ((uint4*)tt)[i] = v;
}

// ---------------- MFMA GEMM (generic bf16): C = A @ Bt^T, BM x 128 tile, dbuf ----------------
// EPI 0: f32 row-major (z-linear via cZ). SPLITK>1: z = zh*SPLITK+zk, K-offset zk*K.
template <int BM, int EPI, int SPLITK = 1>
__global__ __launch_bounds__(256) void gemm_mfma_kernel(const uint16_t* __restrict__ A,
                                                        const uint16_t* __restrict__ Bt,
                                                        void* __restrict__ Cv, int K, int lda,
                                                        int ldb, int ldc, int aZ, int bZ,
                                                        int cZ) {
  constexpr int MT = BM / 32;
  __shared__ __align__(16) uint16_t As[2][BM * 64];
  __shared__ __align__(16) uint16_t Bs[2][128 * 64];
  int z = blockIdx.z;
  if (SPLITK > 1) {
    int zh = z / SPLITK, zk = z % SPLITK;
    A += (size_t)zh * aZ + (size_t)zk * K;
    Bt += (size_t)zh * bZ + (size_t)zk * K;
  } else {
    A += (size_t)z * aZ;
    Bt += (size_t)z * bZ;
  }
  int m0 = blockIdx.x * BM, n0 = blockIdx.y * 128;
  int tid = threadIdx.x;
  int wave = tid >> 6, lane = tid & 63;
  int wm = wave >> 1, wn = wave & 1;
  int rS = lane >> 3, sl = lane & 7;
  int lr = lane >> 4, lc = lane & 15;

  auto stage = [&](int k0, int buf) {
#pragma unroll
    for (int i = 0; i < MT; ++i) {
      int idx = wave * MT + i;
      int row = idx * 8 + rS;
      GLOAD16(A + (size_t)(m0 + row) * lda + k0 + ((sl ^ (row & 7)) << 3),
              (uint8_t*)As[buf] + idx * 1024);
    }
#pragma unroll
    for (int i = 0; i < 4; ++i) {
      int idx = wave * 4 + i;
      int row = idx * 8 + rS;
      GLOAD16(Bt + (size_t)(n0 + row) * ldb + k0 + ((sl ^ (row & 7)) << 3),
              (uint8_t*)Bs[buf] + idx * 1024);
    }
  };

  f32x4 acc[MT][4] = {};
  stage(0, 0);
  int cur = 0;
  for (int k0 = 0; k0 < K; k0 += 64) {
    __syncthreads();
    if (k0 + 64 < K) stage(k0 + 64, cur ^ 1);
    short8 af[MT][2], bf[4][2];
#pragma unroll
    for (int t = 0; t < MT; ++t)
#pragma unroll
      for (int ks = 0; ks < 2; ++ks) {
        int slot = ks * 4 + lr;
        int ra = wm * (BM / 2) + t * 16 + lc;
        af[t][ks] =
            *(const short8*)((const uint8_t*)As[cur] + ra * 128 + ((slot ^ (ra & 7)) << 4));
      }
#pragma unroll
    for (int t = 0; t < 4; ++t)
#pragma unroll
      for (int ks = 0; ks < 2; ++ks) {
        int slot = ks * 4 + lr;
        int rb = wn * 64 + t * 16 + lc;
        bf[t][ks] =
            *(const short8*)((const uint8_t*)Bs[cur] + rb * 128 + ((slot ^ (rb & 7)) << 4));
      }
    __builtin_amdgcn_s_setprio(1);
#pragma unroll
    for (int mt = 0; mt < MT; ++mt)
#pragma unroll
      for (int nt = 0; nt < 4; ++nt) {
        acc[mt][nt] =
            __builtin_amdgcn_mfma_f32_16x16x32_bf16(af[mt][0], bf[nt][0], acc[mt][nt], 0, 0, 0);
        acc[mt][nt] =
            __builtin_amdgcn_mfma_f32_16x16x32_bf16(af[mt][1], bf[nt][1], acc[mt][nt], 0, 0, 0);
      }
    __builtin_amdgcn_s_setprio(0);
    cur ^= 1;
  }
#pragma unroll
  for (int mt = 0; mt < MT; ++mt)
#pragma unroll
    for (int nt = 0; nt < 4; ++nt)
#pragma unroll
      for (int r = 0; r < 4; ++r) {
        int m = m0 + wm * (BM / 2) + mt * 16 + lr * 4 + r;
        int n = n0 + wn * 64 + nt * 16 + lc;
        float v = acc[mt][nt][r];
        if (EPI == 0)
          ((float*)Cv)[(size_t)z * cZ + (size_t)m * ldc + n] = v;
        else
          ((uint16_t*)Cv)[(size_t)z * cZ + (size_t)m * ldc + n] = f2b(v);
      }
}

// ---------------- fold2 fused: A = reduce4(tmp1[head]) in LDS; B = WqT staged ----------------
// grid (1, 16 ntiles, 16 heads), 256 thr. WfoldT[h*64+m][n] = sum_k A[m][k] * WqT[n][h*128+k]
__global__ __launch_bounds__(256) void fold2_kernel(const float* __restrict__ tmp1,
                                                    const uint16_t* __restrict__ WqT,
                                                    uint16_t* __restrict__ WfoldT) {
  __shared__ __align__(16) uint16_t As[2][64 * 64];
  __shared__ __align__(16) uint16_t Bs[2][128 * 64];
  int z = blockIdx.z;
  int n0 = blockIdx.y * 128;
  const uint16_t* Bt = WqT + z * 128;
  int tid = threadIdx.x;
  int wave = tid >> 6, lane = tid & 63;
  int wm = wave >> 1, wn = wave & 1;
  int rS = lane >> 3, sl = lane & 7;
  int lr = lane >> 4, lc = lane & 15;

  // A prefill: sum 4 f32 partials -> bf16, swizzled, into As[0] (k 0..63) and As[1] (k 64..127)
  {
    int row = tid >> 2;
    int kbase = (tid & 3) * 32;
    const float* tp = tmp1 + (size_t)z * 32768 + row * 128;
#pragma unroll
    for (int c = 0; c < 8; ++c) {
      int k4 = kbase + c * 4;
      float4 s = *(const float4*)(tp + k4);
      float4 s1 = *(const float4*)(tp + 8192 + k4);
      float4 s2 = *(const float4*)(tp + 16384 + k4);
      float4 s3 = *(const float4*)(tp + 24576 + k4);
      s.x = ((s.x + s1.x) + s2.x) + s3.x;
      s.y = ((s.y + s1.y) + s2.y) + s3.y;
      s.z = ((s.z + s1.z) + s2.z) + s3.z;
      s.w = ((s.w + s1.w) + s2.w) + s3.w;
      uint32_t lo = cvtpk_bf16(s.x, s.y);
      uint32_t hi = cvtpk_bf16(s.z, s.w);
      int buf = k4 >> 6, kl = k4 & 63;
      int slot = kl >> 3;
      uint32_t addr = row * 128 + ((slot ^ (row & 7)) << 4) + (kl & 7) * 2;
      *(uint32_t*)((uint8_t*)As[buf] + addr) = lo;
      *(uint32_t*)((uint8_t*)As[buf] + addr + 4) = hi;
    }
  }

  auto stageB = [&](int k0, int buf) {
#pragma unroll
    for (int i = 0; i < 4; ++i) {
      int idx = wave * 4 + i;
      int row = idx * 8 + rS;
      GLOAD16(Bt + (size_t)(n0 + row) * 2048 + k0 + ((sl ^ (row & 7)) << 3),
              (uint8_t*)Bs[buf] + idx * 1024);
    }
  };

  f32x4 acc[2][4] = {};
  stageB(0, 0);
  int cur = 0;
  for (int k0 = 0; k0 < 128; k0 += 64) {
    __syncthreads();  // drains gloads AND makes A-prefill ds_writes visible
    if (k0 + 64 < 128) stageB(64, 1);
    short8 af[2][2], bf[4][2];
#pragma unroll
    for (int t = 0; t < 2; ++t)
#pragma unroll
      for (int ks = 0; ks < 2; ++ks) {
        int slot = ks * 4 + lr;
        int ra = wm * 32 + t * 16 + lc;
        af[t][ks] =
            *(const short8*)((const uint8_t*)As[cur] + ra * 128 + ((slot ^ (ra & 7)) << 4));
      }
#pragma unroll
    for (int t = 0; t < 4; ++t)
#pragma unroll
      for (int ks = 0; ks < 2; ++ks) {
        int slot = ks * 4 + lr;
        int rb = wn * 64 + t * 16 + lc;
        bf[t][ks] =
            *(const short8*)((const uint8_t*)Bs[cur] + rb * 128 + ((slot ^ (rb & 7)) << 4));
      }
    __builtin_amdgcn_s_setprio(1);
#pragma unroll
    for (int mt = 0; mt < 2; ++mt)
#pragma unroll
      for (int nt = 0; nt < 4; ++nt) {
        acc[mt][nt] =
            __builtin_amdgcn_mfma_f32_16x16x32_bf16(af[mt][0], bf[nt][0], acc[mt][nt], 0, 0, 0);
        acc[mt][nt] =
            __builtin_amdgcn_mfma_f32_16x16x32_bf16(af[mt][1], bf[nt][1], acc[mt][nt], 0, 0, 0);
      }
    __builtin_amdgcn_s_setprio(0);
    cur ^= 1;
  }
#pragma unroll
  for (int mt = 0; mt < 2; ++mt)
#pragma unroll
    for (int nt = 0; nt < 4; ++nt)
#pragma unroll
      for (int r = 0; r < 4; ++r) {
        int m = wm * 32 + mt * 16 + lr * 4 + r;
        int n = n0 + wn * 64 + nt * 16 + lc;
        WfoldT[(size_t)z * 131072 + (size_t)m * 2048 + n] = f2b(acc[mt][nt][r]);
      }
}

// ---------------- triple GEMM: qr (y<8) | kr (y<16) | VhT (y<32) in one launch ----------------
// grid (32, 32), 256 thr. qr: rope_q(hqb @ WfoldT^T); kr: rope_k(kvb @ WkrT^T);
// VhT: kvb @ wkvb^T in VhT layout. All operands bf16 via global_load_lds.
__global__ __launch_bounds__(256) void gemm_triple_kernel(
    const uint16_t* __restrict__ hqb, const uint16_t* __restrict__ WfoldT,
    uint16_t* __restrict__ qrb, const uint16_t* __restrict__ kvb,
    const uint16_t* __restrict__ WkrT, uint16_t* __restrict__ krb,
    const uint16_t* __restrict__ wkvb, uint16_t* __restrict__ VhT,
    const float* __restrict__ cosQ, const float* __restrict__ sinQ,
    const float* __restrict__ cosK, const float* __restrict__ sinK) {
  __shared__ __align__(16) uint16_t As[2][64 * 64];
  __shared__ __align__(16) uint16_t Bs[2][128 * 64];
  int bx = blockIdx.x, byr = blockIdx.y;
  const uint16_t *A, *Bt;
  uint16_t* Cv;
  const float *rc, *rs;
  int K, lda, ldb, n0, mode;  // mode 0: rope bf16 (ldc=1024); 1: VhT layout
  if (byr < 8) {
    A = hqb; Bt = WfoldT; Cv = qrb; K = 2048; lda = 2048; ldb = 2048;
    n0 = byr * 128; mode = 0; rc = cosQ; rs = sinQ;
  } else if (byr < 16) {
    A = kvb; Bt = WkrT; Cv = krb; K = 512; lda = 512; ldb = 512;
    n0 = (byr - 8) * 128; mode = 0; rc = cosK; rs = sinK;
  } else {
    A = kvb; Bt = wkvb; Cv = VhT; K = 512; lda = 512; ldb = 512;
    n0 = (byr - 16) * 128; mode = 1; rc = nullptr; rs = nullptr;
  }
  int m0 = bx * 64;
  int tid = threadIdx.x;
  int wave = tid >> 6, lane = tid & 63;
  int wm = wave >> 1, wn = wave & 1;
  int rS = lane >> 3, sl = lane & 7;
  int lr = lane >> 4, lc = lane & 15;

  auto stage = [&](int k0, int buf) {
#pragma unroll
    for (int i = 0; i < 2; ++i) {
      int idx = wave * 2 + i;
      int row = idx * 8 + rS;
      GLOAD16(A + (size_t)(m0 + row) * lda + k0 + ((sl ^ (row & 7)) << 3),
              (uint8_t*)As[buf] + idx * 1024);
    }
#pragma unroll
    for (int i = 0; i < 4; ++i) {
      int idx = wave * 4 + i;
      int row = idx * 8 + rS;
      GLOAD16(Bt + (size_t)(n0 + row) * ldb + k0 + ((sl ^ (row & 7)) << 3),
              (uint8_t*)Bs[buf] + idx * 1024);
    }
  };

  f32x4 acc[2][4] = {};
  stage(0, 0);
  int cur = 0;
  for (int k0 = 0; k0 < K; k0 += 64) {
    __syncthreads();
    if (k0 + 64 < K) stage(k0 + 64, cur ^ 1);
    short8 af[2][2], bf[4][2];
#pragma unroll
    for (int t = 0; t < 2; ++t)
#pragma unroll
      for (int ks = 0; ks < 2; ++ks) {
        int slot = ks * 4 + lr;
        int ra = wm * 32 + t * 16 + lc;
        af[t][ks] =
            *(const short8*)((const uint8_t*)As[cur] + ra * 128 + ((slot ^ (ra & 7)) << 4));
      }
#pragma unroll
    for (int t = 0; t < 4; ++t)
#pragma unroll
      for (int ks = 0; ks < 2; ++ks) {
        int slot = ks * 4 + lr;
        int rb = wn * 64 + t * 16 + lc;
        bf[t][ks] =
            *(const short8*)((const uint8_t*)Bs[cur] + rb * 128 + ((slot ^ (rb & 7)) << 4));
      }
    __builtin_amdgcn_s_setprio(1);
#pragma unroll
    for (int mt = 0; mt < 2; ++mt)
#pragma unroll
      for (int nt = 0; nt < 4; ++nt) {
        acc[mt][nt] =
            __builtin_amdgcn_mfma_f32_16x16x32_bf16(af[mt][0], bf[nt][0], acc[mt][nt], 0, 0, 0);
        acc[mt][nt] =
            __builtin_amdgcn_mfma_f32_16x16x32_bf16(af[mt][1], bf[nt][1], acc[mt][nt], 0, 0, 0);
      }
    __builtin_amdgcn_s_setprio(0);
    cur ^= 1;
  }
  if (mode == 0) {
#pragma unroll
    for (int mt = 0; mt < 2; ++mt)
#pragma unroll
      for (int nt = 0; nt < 4; ++nt)
#pragma unroll
        for (int r = 0; r < 4; ++r) {
          int m = m0 + wm * 32 + mt * 16 + lr * 4 + r;
          int n = n0 + wn * 64 + nt * 16 + lc;
          int pos = m & 1023, j = n & 63;
          float x = acc[mt][nt][r];
          float prt = acc[mt][nt ^ 2][r];
          float rot = (nt & 2) ? prt : -prt;
          float v = fmaf(x, rc[pos * 64 + j], rot * rs[pos * 64 + j]);
          Cv[(size_t)m * 1024 + n] = f2b(v);
        }
  } else {
#pragma unroll
    for (int mt = 0; mt < 2; ++mt)
#pragma unroll
      for (int nt = 0; nt < 4; ++nt)
#pragma unroll
        for (int r = 0; r < 4; ++r) {
          int m = m0 + wm * 32 + mt * 16 + lr * 4 + r;
          int n = n0 + wn * 64 + nt * 16 + lc;
          Cv[((size_t)((m >> 10) * 2048 + n)) * 1024 + (m & 1023)] = f2b(acc[mt][nt][r]);
        }
  }
}

// ---------------- MFMA flash attention, swapped QK^T, Q-split 8 waves, FIXED-MAX softmax ----
// grid (bh=32, stile=8), 512 thr = 8 waves; wave owns q-rows s0 + wave*16 .. +15; all waves share
// one dbuf K/V tile (3 gloads/wave), ONE barrier/iter, prefetch-under-compute.
// Softmax uses FIXED max M=8 (exp2 domain; exact by shift-invariance — scores are O(1)).
// Out: ctxlatb bf16 [b*1024+s][2048]
__global__ __launch_bounds__(512, 2) void flash3_kernel(const uint16_t* __restrict__ qrb,
                                                        const uint16_t* __restrict__ krb,
                                                        const uint16_t* __restrict__ VhT,
                                                        uint16_t* __restrict__ ctxlatb) {
  // LDS: Ks[2][8192] @0 | Vs[2][16384] @16384 | Ps[8][2304] @49152  (total 67584 B)
  __shared__ __align__(16) uint8_t lds[67584];
  int bh = blockIdx.x;
  int b = bh >> 4, h = bh & 15;
  int s0 = blockIdx.y * 128;
  int tid = threadIdx.x, wave = tid >> 6, lane = tid & 63;
  int lr = lane >> 4, lc = lane & 15;
  int rS = lane >> 3, sl = lane & 7;

  uint8_t* Ps = lds + 49152 + wave * 2304;

  const uint16_t* qrow = qrb + (size_t)(b * 1024 + s0 + wave * 16 + lc) * 1024 + h * 64;
  short8 qa[2];
  qa[0] = *(const short8*)(qrow + lr * 8);
  qa[1] = *(const short8*)(qrow + 32 + lr * 8);

  float l_run = 0.f;
  f32x4 o[8] = {};

  uint8_t* psW = Ps + lc * 144 + lr * 8;
  const uint8_t* psR = Ps + lc * 144 + lr * 16;

  const uint16_t* krbase = krb + (size_t)(b * 1024) * 1024 + h * 64;
  const uint16_t* vtbase = VhT + (size_t)(b * 2048 + h * 128) * 1024;

  auto stageKV = [&](int l0, int buf) {
#pragma unroll
    for (int i = 0; i < 3; ++i) {
      int g = wave * 3 + i;
      if (g < 8) {
        int row = g * 8 + rS;
        GLOAD16(krbase + (size_t)(l0 + row) * 1024 + ((sl ^ (row & 7)) << 3),
                lds + buf * 8192 + g * 1024);
      } else {
        int v = g - 8;
        int row = v * 8 + rS;
        GLOAD16(vtbase + (size_t)row * 1024 + l0 + ((sl ^ (row & 7)) << 3),
                lds + 16384 + buf * 16384 + v * 1024);
      }
    }
  };

  stageKV(0, 0);
  int cur = 0;
  for (int t = 0; t < 16; ++t) {
    __syncthreads();
    if (t < 15) stageKV((t + 1) * 64, cur ^ 1);
    const uint8_t* Ks = lds + cur * 8192;
    const uint8_t* Vs = lds + 16384 + cur * 16384;

    f32x4 sc[4];
    __builtin_amdgcn_s_setprio(1);
#pragma unroll
    for (int nt = 0; nt < 4; ++nt) {
      int rowk = nt * 16 + lc;
      short8 kb0 = *(const short8*)(Ks + rowk * 128 + ((lr ^ (rowk & 7)) << 4));
      short8 kb1 = *(const short8*)(Ks + rowk * 128 + (((4 + lr) ^ (rowk & 7)) << 4));
      f32x4 z = {};
      z = __builtin_amdgcn_mfma_f32_16x16x32_bf16(kb0, qa[0], z, 0, 0, 0);
      sc[nt] = __builtin_amdgcn_mfma_f32_16x16x32_bf16(kb1, qa[1], z, 0, 0, 0);
    }
    __builtin_amdgcn_s_setprio(0);

    float ps = 0.f;
#pragma unroll
    for (int nt = 0; nt < 4; ++nt) {
#pragma unroll
      for (int rp = 0; rp < 2; ++rp) {
        float p0 = exp2f(sc[nt][rp * 2] - 8.0f);
        float p1 = exp2f(sc[nt][rp * 2 + 1] - 8.0f);
        ps += p0 + p1;
        *(uint32_t*)(psW + nt * 32 + rp * 4) = cvtpk_bf16(p0, p1);
      }
    }
    l_run += ps;

    short8 pa[2];
    pa[0] = *(const short8*)(psR);
    pa[1] = *(const short8*)(psR + 64);
    __builtin_amdgcn_s_setprio(1);
#pragma unroll
    for (int nt = 0; nt < 8; ++nt) {
      int rowv = nt * 16 + lc;
      short8 vb0 = *(const short8*)(Vs + rowv * 128 + ((lr ^ (rowv & 7)) << 4));
      short8 vb1 = *(const short8*)(Vs + rowv * 128 + (((4 + lr) ^ (rowv & 7)) << 4));
      o[nt] = __builtin_amdgcn_mfma_f32_16x16x32_bf16(pa[0], vb0, o[nt], 0, 0, 0);
      o[nt] = __builtin_amdgcn_mfma_f32_16x16x32_bf16(pa[1], vb1, o[nt], 0, 0, 0);
    }
    __builtin_amdgcn_s_setprio(0);
    cur ^= 1;
  }

  l_run += __shfl_xor(l_run, 16);
  l_run += __shfl_xor(l_run, 32);
  float li[4];
#pragma unroll
  for (int r = 0; r < 4; ++r) li[r] = 1.0f / __shfl(l_run, lr * 4 + r);
  uint16_t* orow = ctxlatb + (size_t)(b * 1024 + s0 + wave * 16) * 2048 + h * 128;
#pragma unroll
  for (int nt = 0; nt < 8; ++nt)
#pragma unroll
    for (int r = 0; r < 4; ++r)
      orow[(size_t)(lr * 4 + r) * 2048 + nt * 16 + lc] = f2b(o[nt][r] * li[r]);
}

extern "C" void kernel_launch(void* const* d_in, const int* in_sizes, int n_in,
                              void* d_out, int out_size, void* d_ws, size_t ws_size,
                              hipStream_t stream) {
  const float* hidden_q = (const float*)d_in[0];
  const float* kv_c = (const float*)d_in[1];
  const float* Wq = (const float*)d_in[2];
  const float* w_kc_q = (const float*)d_in[3];
  const float* W_qr = (const float*)d_in[4];
  const float* W_kr = (const float*)d_in[5];
  const float* w_kc_kv = (const float*)d_in[6];
  const float* Wo = (const float*)d_in[7];
  float* out = (float*)d_out;

  const size_t MB = 1024 * 1024;
  uint8_t* base = (uint8_t*)d_ws;
  // --- live through flash ---
  uint16_t* Wob = (uint16_t*)(base + 0 * MB);       // 8 MiB
  uint16_t* qrb = (uint16_t*)(base + 8 * MB);       // 4 MiB [2048][1024] (q pre-scaled log2e)
  uint16_t* krb = (uint16_t*)(base + 12 * MB);      // 4 MiB [2048][1024]
  uint16_t* VhT = (uint16_t*)(base + 16 * MB);      // 8 MiB [b*2048+h*128+kk][1024]
  uint16_t* ctxlatb = (uint16_t*)(base + 24 * MB);  // 8 MiB [b*1024+s][2048]
  // --- prep stage (dead by flash time) ---
  float* cosK = (float*)(base + 32 * MB);
  float* sinK = (float*)(base + 32 * MB + 262144);
  float* cosQ = (float*)(base + 32 * MB + 524288);
  float* sinQ = (float*)(base + 32 * MB + 786432);
  uint16_t* hqb = (uint16_t*)(base + 33 * MB);      // 8 MiB
  uint16_t* kvb = (uint16_t*)(base + 41 * MB);      // 2 MiB
  uint16_t* wkvb = (uint16_t*)(base + 43 * MB);     // 2 MiB
  uint16_t* WqT = (uint16_t*)(base + 45 * MB);      // 8 MiB
  uint16_t* WqrT = (uint16_t*)(base + 53 * MB);     // 3 MiB
  uint16_t* wkcqb = (uint16_t*)(base + 56 * MB);    // 6 MiB
  float* tmp1 = (float*)(base + 62 * MB);           // 2 MiB f32 fold1 partials [16][4][8192]
  uint16_t* WkrT = (uint16_t*)(base + 64 * MB + 262144);  // 1 MiB

  // fused prep: 5 converts + rope tables + 3 transposes (13056 blocks)
  prep_kernel<<<dim3(13056), dim3(256), 0, stream>>>(
      hidden_q, hqb, kv_c, kvb, w_kc_kv, wkvb, Wo, Wob, w_kc_q, wkcqb, cosK, sinK, cosQ, sinQ, Wq,
      WqT, (const float*)W_qr, WqrT, (const float*)W_kr, WkrT);
  // fold1 split-K x4: tmp1[h*4+zk] = partial sum over q in [zk*384,(zk+1)*384)
  gemm_mfma_kernel<64, 0, 4><<<dim3(1, 1, 64), dim3(256), 0, stream>>>(
      WqrT, wkcqb, tmp1, 384, 1536, 1536, 128, 98304, 196608, 8192);
  // fold2 (fused 4-partial reduce in A-prefill): WfoldT[h*64+r][d]
  uint16_t* WfoldT = wkcqb;  // overlays wkcqb (dead after fold1)
  fold2_kernel<<<dim3(1, 16, 16), dim3(256), 0, stream>>>(tmp1, WqT, WfoldT);
  // triple GEMM: qr (rope_q) + kr (rope_k) + VhT in one launch (1024 blocks)
  gemm_triple_kernel<<<dim3(32, 32), dim3(256), 0, stream>>>(
      hqb, WfoldT, qrb, kvb, WkrT, krb, wkvb, VhT, cosQ, sinQ, cosK, sinK);
  // fused flash attention (Q-split 8 waves, shared dbuf staging, fixed-max softmax) -> ctxlatb
  flash3_kernel<<<dim3(32, 8), dim3(512), 0, stream>>>(qrb, krb, VhT, ctxlatb);
  // out = ctxlatb @ Wob^T  [2048][2048] f32
  gemm_mfma_kernel<64, 0><<<dim3(32, 16), dim3(256), 0, stream>>>(ctxlatb, Wob, out, 2048, 2048,
                                                                  2048, 2048, 0, 0, 0);
}